// Round 6
// baseline (3091.230 us; speedup 1.0000x reference)
//
#include <hip/hip_runtime.h>

#define N_NODES 50000
#define N_EDGES 1600000
#define CAP 64            // bucket capacity per node; Poisson(32) tail @64 ~ 1e-7
#define OVF_CAP 8192

// Binned build parameters
#define BIN_SHIFT 7
#define BIN_NODES 128               // nodes per bin = 1<<BIN_SHIFT
#define NBINS 391                   // ceil(50000/128)
#define BIN_CAP 5120                // mean 4092, sigma ~64 -> 16 sigma headroom
#define EPB 4096                    // edges per k_part block

// Phase-tiled persistent attention parameters
#define NBLK_C 768                  // 3 blocks/CU x 256 CU -> co-resident
#define NWAVES_C 3072               // NBLK_C * 4 waves
#define NSLOT 17                    // ceil(50000/3072) nodes per wave
#define NPH 8                       // src phases
#define TILE_N 6250                 // src nodes per phase; KV tile = 3.2 MB < 4 MB L2

// Workspace element offsets (4-byte units). Peak ~77.4 MB.
#define O_CNTO   0         // int[50000]  out-degree
#define O_CNTI   50000     // int[50000]  in-degree (also bucket fill)
#define O_OVFN   100000    // int[1]      overflow count
#define O_OVF    100002    // int2[8192]  overflow (dst,src) pairs
#define O_BINC   116400    // int[391]    per-bin edge count (ends 116791)
#define O_PHC    116800    // int[8]      phase barrier counters (ends 116808 < 120000)
#define O_BUCKET 120000    // int[50000*64] src per slot
#define O_HB     3320000   // uint[3.2M]  bf16x2 h*norm_out
#define O_AGGB   6520000   // uint[3.2M]  bf16x2 agg rows (256 B/node)
#define O_WT     9720000   // uint[24576] bf16 W^T for Q,K,V: [3][128 n][64 k-pairs]
#define O_QB     9750000   // uint[3.2M]  bf16x2 Q rows (64 uints/node)
#define O_KV     12950000  // uint[6.4M]  interleaved bf16 K/V rows (512 B/node)
// pairs overlays hb/aggb: written by k_part, dead after k_bins, before k_hb/k_agg write
#define O_PAIRS  3320000   // int2[391*5120] = 16.0 MB, ends at float-ofs 7323840 < O_WT

typedef unsigned int uint;
typedef unsigned long long ulong64;
typedef __attribute__((ext_vector_type(8))) short short8;
typedef __attribute__((ext_vector_type(4))) float floatx4;

union U16 { uint4 u; short8 s; };

__device__ __forceinline__ uint f2bf2(float a, float b) {
    uint ua = __float_as_uint(a); ua = (ua + 0x7fffu + ((ua >> 16) & 1u)) >> 16;
    uint ub = __float_as_uint(b); ub = (ub + 0x7fffu + ((ub >> 16) & 1u)) >> 16;
    return ua | (ub << 16);
}
__device__ __forceinline__ float bflo(uint u) { return __uint_as_float(u << 16); }
__device__ __forceinline__ float bfhi(uint u) { return __uint_as_float(u & 0xffff0000u); }

// DPP cross-lane: VALU-only (no ds_bpermute, no lgkmcnt stalls).
// 0xB1 = quad_perm(1,0,3,2) = xor1; 0x4E = quad_perm(2,3,0,1) = xor2;
// 0x141 = row_half_mirror = xor7 within 8 (== xor4 once quads are uniform).
template<int CTRL>
__device__ __forceinline__ float dpp_add8(float x) {
    int t = __builtin_amdgcn_update_dpp(0, __float_as_int(x), CTRL, 0xF, 0xF, true);
    return x + __int_as_float(t);
}
__device__ __forceinline__ float dpp_xor1(float x) {
    int t = __builtin_amdgcn_update_dpp(0, __float_as_int(x), 0xB1, 0xF, 0xF, true);
    return __int_as_float(t);
}

// Phase A: bin edges by dst>>7. LDS histogram -> chunked global reservation ->
// scatter (dst,src) pairs into per-bin arrays.
__global__ __launch_bounds__(256) void k_part(const int* __restrict__ src,
                                              const int* __restrict__ dst,
                                              int* cnt_out,
                                              int* bin_cnt,
                                              int2* __restrict__ pairs) {
    __shared__ int hist[NBINS];
    __shared__ int base[NBINS];
    const int t = threadIdx.x;
    const int e0 = blockIdx.x * EPB;

    for (int b = t; b < NBINS; b += 256) hist[b] = 0;
    __syncthreads();

    #pragma unroll
    for (int i = 0; i < EPB / 256; ++i) {
        int e = e0 + i * 256 + t;
        if (e < N_EDGES) {
            int d = dst[e];
            atomicAdd(&hist[d >> BIN_SHIFT], 1);
            atomicAdd(&cnt_out[src[e]], 1);
        }
    }
    __syncthreads();

    for (int b = t; b < NBINS; b += 256) {
        base[b] = atomicAdd(&bin_cnt[b], hist[b]);
        hist[b] = 0;                  // reuse as cursor
    }
    __syncthreads();

    #pragma unroll
    for (int i = 0; i < EPB / 256; ++i) {
        int e = e0 + i * 256 + t;
        if (e < N_EDGES) {
            int d = dst[e], s = src[e];
            int bin = d >> BIN_SHIFT;
            int idx = base[bin] + atomicAdd(&hist[bin], 1);
            if (idx < BIN_CAP)
                pairs[(size_t)bin * BIN_CAP + idx] = make_int2(d, s);
        }
    }
}

// Phase B: one block per bin; LDS-atomic position assignment; then bitonic-sort
// each bucket row by src id. Sorted rows make each phase's entries a contiguous
// prefix range -> cursor-based phase processing in k_attn_coop.
__global__ __launch_bounds__(256) void k_bins(const int* __restrict__ bin_cnt,
                                              const int2* __restrict__ pairs,
                                              int* __restrict__ cnt_in,
                                              int* __restrict__ bucket,
                                              int* ovf_n, int2* __restrict__ ovf) {
    __shared__ int lcnt[BIN_NODES];
    const int b = blockIdx.x;
    const int t = threadIdx.x;
    for (int i = t; i < BIN_NODES; i += 256) lcnt[i] = 0;
    __syncthreads();

    const int nb = min(bin_cnt[b], BIN_CAP);
    const int2* pp = pairs + (size_t)b * BIN_CAP;
    for (int i = t; i < nb; i += 256) {
        int2 p = pp[i];                        // p.x = dst, p.y = src
        int pos = atomicAdd(&lcnt[p.x & (BIN_NODES - 1)], 1);
        if (pos < CAP) {
            bucket[((size_t)p.x << 6) + pos] = p.y;
        } else {                               // statistically never; safety net
            int o = atomicAdd(ovf_n, 1);
            if (o < OVF_CAP) ovf[o] = p;
        }
    }
    __syncthreads();

    const int node0 = b << BIN_SHIFT;
    for (int i = t; i < BIN_NODES; i += 256) {
        int n = node0 + i;
        if (n < N_NODES) cnt_in[n] = lcnt[i];  // total count incl. overflow
    }
    __syncthreads();

    // Bitonic sort of each bucket row (64 lanes, 21 compare-exchange steps).
    const int wv = t >> 6, ln = t & 63;
    for (int q = wv; q < BIN_NODES; q += 4) {
        int n = node0 + q;
        if (n >= N_NODES) continue;
        int m = min(lcnt[q], CAP);
        if (m <= 1) continue;
        int* br = bucket + ((size_t)n << 6);
        int v = (ln < m) ? br[ln] : 0x7fffffff;   // sentinel sorts to the top
        #pragma unroll
        for (int k = 2; k <= 64; k <<= 1) {
            #pragma unroll
            for (int j = k >> 1; j > 0; j >>= 1) {
                int p = __shfl_xor(v, j);
                bool keepMin = (((ln & j) == 0) == ((ln & k) == 0));
                v = keepMin ? min(v, p) : max(v, p);
            }
        }
        if (ln < m) br[ln] = v;
    }
}

// W^T cast: wt[y][n][k2] = bf16x2(W_y[2k2][n], W_y[2k2+1][n])
__global__ __launch_bounds__(256) void k_wt(const float* __restrict__ WQ,
                                            const float* __restrict__ WK,
                                            const float* __restrict__ WV,
                                            uint* __restrict__ wt) {
    int idx = blockIdx.x * 256 + threadIdx.x;   // [0, 3*8192)
    if (idx < 3 * 8192) {
        int y = idx >> 13;
        int rem = idx & 8191;
        int k2 = rem >> 7;          // 0..63
        int n  = rem & 127;         // coalesced reads
        const float* W = (y == 0) ? WQ : (y == 1) ? WK : WV;
        float a = W[(2 * k2) * 128 + n];
        float b = W[(2 * k2 + 1) * 128 + n];
        wt[(y << 13) + (n << 6) + k2] = f2bf2(a, b);
    }
}

// hb[n][j] = bf16(h[n][j] * rsqrt(max(deg_out,1)))
__global__ __launch_bounds__(256) void k_hb(const float* __restrict__ h,
                                            const int* __restrict__ cnt_out,
                                            uint* __restrict__ hb) {
    int idx = blockIdx.x * 256 + threadIdx.x;   // [0, N*64)
    if (idx < N_NODES * 64) {
        int n = idx >> 6;
        float no = rsqrtf(fmaxf((float)cnt_out[n], 1.0f));
        float2 hv = *(const float2*)(h + ((size_t)idx << 1));
        hb[idx] = f2bf2(hv.x * no, hv.y * no);
    }
}

// aggb[n] = bf16( rsqrt(max(deg_in,1)) * sum_{slots of n} hb[s] )
__global__ __launch_bounds__(256) void k_agg(
    const int* __restrict__ cnt_in, const int* __restrict__ bucket,
    const int* __restrict__ ovf_n, const int2* __restrict__ ovf,
    const uint* __restrict__ hb, uint* __restrict__ aggb)
{
    int n = blockIdx.x * 4 + (threadIdx.x >> 6);
    int lane = threadIdx.x & 63;
    int cnt = cnt_in[n];
    int m = min(cnt, CAP);
    const int* b = bucket + ((size_t)n << 6);
    int s_own = b[lane];                 // whole bucket row, one coalesced load
    float ax = 0.f, ay = 0.f;

    if (m > 0) {
        uint uA[16], uB[16];
        const int nb = (m + 15) >> 4;
        const int mm1 = m - 1;

#define AGLD(P, base) do { _Pragma("unroll")                                   \
        for (int j = 0; j < 16; ++j) {                                         \
            int sj = __builtin_amdgcn_readlane(s_own, min((base) + j, mm1));   \
            P[j] = hb[((uint)sj << 6) + (uint)lane];                           \
        } } while (0)
#define AGCMP(P, base) do { _Pragma("unroll")                                  \
        for (int j = 0; j < 16; ++j) {                                         \
            if ((base) + j < m) { ax += bflo(P[j]); ay += bfhi(P[j]); }        \
        } } while (0)

        AGLD(uA, 0);
        int t = 0;
        while (t + 1 < nb) {
            AGLD(uB, (t + 1) << 4);
            AGCMP(uA, t << 4);
            ++t;
            if (t + 1 < nb) {
                AGLD(uA, (t + 1) << 4);
                AGCMP(uB, t << 4);
                ++t;
            } else {
                AGCMP(uB, t << 4);
                ++t;
                break;
            }
        }
        if (t < nb) { AGCMP(uA, t << 4); }
#undef AGLD
#undef AGCMP
    }

    if (cnt > CAP) {                       // statistically never; correctness net
        int on = min(*ovf_n, OVF_CAP);
        for (int j = 0; j < on; ++j) {
            int2 p = ovf[j];
            if (p.x == n) {
                uint u = hb[((uint)p.y << 6) + (uint)lane];
                ax += bflo(u);
                ay += bfhi(u);
            }
        }
    }
    float ni = rsqrtf(fmaxf((float)cnt, 1.0f));
    aggb[((size_t)n << 6) + lane] = f2bf2(ax * ni, ay * ni);
}

// Fused QKV projection via bf16 MFMA. grid (391, 3): y=0 -> qb (bf16 rows),
// y=1 -> K half of interleaved kv, y=2 -> V half.
__global__ __launch_bounds__(256) void k_qkv(
    const uint* __restrict__ aggb, const uint* __restrict__ wt,
    const float* __restrict__ bQ, const float* __restrict__ bK,
    const float* __restrict__ bV,
    uint* __restrict__ qb, uint* __restrict__ kv)
{
    const int y = blockIdx.y;
    const int row0 = blockIdx.x * 128;
    const float* bias = (y == 0) ? bQ : (y == 1) ? bK : bV;

    __shared__ uint sA[128 * 68];   // A tile, row stride 68 uints

    const int t = threadIdx.x;
    for (int idx = t; idx < 128 * 16; idx += 256) {
        int r = idx >> 4, c4 = (idx & 15) << 2;
        int row = row0 + r;
        uint4 v = make_uint4(0u, 0u, 0u, 0u);
        if (row < N_NODES) v = *(const uint4*)(aggb + ((size_t)row << 6) + c4);
        *(uint4*)(&sA[r * 68 + c4]) = v;
    }
    __syncthreads();

    const int wave = t >> 6;
    const int lane = t & 63;
    const int mrow = lane & 15;     // m (A) / n (B) / col (C)
    const int kq   = lane >> 4;     // 0..3
    const int mbase = wave * 32;
    const uint* wty = wt + (y << 13);

    floatx4 acc[2][8];
    for (int a = 0; a < 2; ++a)
        for (int b = 0; b < 8; ++b)
            acc[a][b] = (floatx4){0.f, 0.f, 0.f, 0.f};

    for (int kc = 0; kc < 128; kc += 32) {
        int koff = (kc >> 1) + (kq << 2);    // uint offset within a row
        short8 afr[2], bfr[8];
        for (int mt = 0; mt < 2; ++mt) {
            U16 u; u.u = *(const uint4*)(&sA[(mbase + mt * 16 + mrow) * 68 + koff]);
            afr[mt] = u.s;
        }
        for (int nt = 0; nt < 8; ++nt) {
            U16 u; u.u = *(const uint4*)(wty + ((nt * 16 + mrow) << 6) + koff);
            bfr[nt] = u.s;
        }
        for (int mt = 0; mt < 2; ++mt)
            for (int nt = 0; nt < 8; ++nt)
                acc[mt][nt] = __builtin_amdgcn_mfma_f32_16x16x32_bf16(
                    afr[mt], bfr[nt], acc[mt][nt], 0, 0, 0);
    }

    // C/D: col = lane&15 (= mrow), row = kq*4 + reg. Pack pairs via DPP xor1.
    if (y == 0) {
        for (int mt = 0; mt < 2; ++mt) {
            int rbase = row0 + mbase + mt * 16 + kq * 4;
            for (int nt = 0; nt < 8; ++nt) {
                int c = nt * 16 + mrow;
                float bv = bias[c];
                for (int r = 0; r < 4; ++r) {
                    float v = fmaxf(acc[mt][nt][r] + bv, 0.f);
                    float pv = dpp_xor1(v);
                    int row = rbase + r;
                    if (((lane & 1) == 0) && row < N_NODES)
                        qb[((size_t)row << 6) + (c >> 1)] = f2bf2(v, pv);
                }
            }
        }
    } else {
        const int vo = (y == 2) ? 1 : 0;
        for (int mt = 0; mt < 2; ++mt) {
            int rbase = row0 + mbase + mt * 16 + kq * 4;
            for (int nt = 0; nt < 8; ++nt) {
                int c = nt * 16 + mrow;    // even for even lanes
                float bv = bias[c];
                for (int r = 0; r < 4; ++r) {
                    float v = fmaxf(acc[mt][nt][r] + bv, 0.f);
                    float pv = dpp_xor1(v);
                    int row = rbase + r;
                    if (((lane & 1) == 0) && row < N_NODES)
                        kv[((size_t)row << 7) + c + vo] = f2bf2(v, pv);
                }
            }
        }
    }
}

// score path: p-scale folded with log2(e); clamp at +/-10*log2(e); raw v_exp_f32.
#define SC_MUL 0.36067376022243085f   // 0.25 * log2(e)
#define SC_CLP 14.426950408889634f    // 10.0 * log2(e)

__device__ __forceinline__ void attn_step(uint2 kvp, float qx, float qy,
                                          float& ax, float& ay, float& zacc) {
    float p = bflo(kvp.x) * qx + bfhi(kvp.x) * qy;
    p = dpp_add8<0xB1>(p);    // + xor1
    p = dpp_add8<0x4E>(p);    // + xor2
    p = dpp_add8<0x141>(p);   // + xor7 (quad-uniform => == xor4)
    float tt = fminf(fmaxf(p * SC_MUL, -SC_CLP), SC_CLP);
    float sc;
    asm("v_exp_f32 %0, %1" : "=v"(sc) : "v"(tt));   // D = 2^S0
    ax += bflo(kvp.y) * sc;
    ay += bfhi(kvp.y) * sc;
    zacc += sc;
}

// Phase-tiled persistent attention, v2.
// - accumulators live in LDS (strictly per-lane -> no sync needed); register
//   state is only s/qx/qy/cursor per slot -> no spills (r5's 84-VGPR spill bug).
// - buckets are SORTED by src (k_bins) -> each phase's entries are a contiguous
//   prefix range per slot, tracked by a cursor; batch-8 clamped loads give
//   8-deep MLP; compute is under wave-uniform branches (no wasted lanes).
// - phase barrier polls with s_sleep (no spin storm); perf-only, bounded,
//   cannot deadlock; stale counters (replay) just make it a no-op.
__global__ __launch_bounds__(256, 3) void k_attn_coop(
    const int* __restrict__ cnt_in, const int* __restrict__ bucket,
    const int* __restrict__ ovf_n, const int2* __restrict__ ovf,
    const uint* __restrict__ qb, const uint* __restrict__ kv,
    int* phc, float* __restrict__ out)
{
    __shared__ float accs[4][NSLOT][3][64];   // 52224 B

    const int lane = threadIdx.x & 63;
    const int wv = threadIdx.x >> 6;
    const int wg = blockIdx.x * 4 + wv;
    const uint loff = (uint)(lane << 1);

    int   s[NSLOT];
    float qx[NSLOT], qy[NSLOT];
    int   cur[NSLOT];

    #pragma unroll
    for (int k = 0; k < NSLOT; ++k) {
        const int n = wg + k * NWAVES_C;
        s[k] = 0x7fffffff;
        qx[k] = 0.f; qy[k] = 0.f;
        cur[k] = 0;
        accs[wv][k][0][lane] = 0.f;
        accs[wv][k][1][lane] = 0.f;
        accs[wv][k][2][lane] = 0.f;
        if (n < N_NODES) {
            int cnt = cnt_in[n];
            int m = min(cnt, CAP);
            int sv = bucket[((size_t)n << 6) + lane];
            if (lane < m) s[k] = sv;            // lanes >= m keep sentinel
            uint qu = qb[((size_t)n << 6) + lane];
            qx[k] = bflo(qu); qy[k] = bfhi(qu);
        }
    }

    for (int ph = 0; ph < NPH; ++ph) {
        const uint hi = (uint)((ph + 1) * TILE_N);

        #pragma unroll
        for (int k = 0; k < NSLOT; ++k) {
            ulong64 blt = __ballot((uint)s[k] < hi);
            int e0 = __popcll(blt);             // sorted -> prefix count
            int b0 = cur[k];
            if (e0 > b0) {
                float lax = 0.f, lay = 0.f, lz = 0.f;
                for (int c0 = b0; c0 < e0; c0 += 8) {
                    uint2 P[8];
                    #pragma unroll
                    for (int j = 0; j < 8; ++j) {
                        int idx = c0 + j; if (idx > e0 - 1) idx = e0 - 1;
                        int sj = __builtin_amdgcn_readlane(s[k], idx);
                        P[j] = *(const uint2*)(kv + (((uint)sj << 7) + loff));
                    }
                    #pragma unroll
                    for (int j = 0; j < 8; ++j)
                        if (c0 + j < e0)        // wave-uniform -> scalar branch
                            attn_step(P[j], qx[k], qy[k], lax, lay, lz);
                }
                accs[wv][k][0][lane] += lax;
                accs[wv][k][1][lane] += lay;
                accs[wv][k][2][lane] += lz;
                cur[k] = e0;
            }
        }

        if (ph + 1 < NPH) {                     // perf-only temporal barrier
            __syncthreads();
            if (threadIdx.x == 0) {
                __hip_atomic_fetch_add(&phc[ph], 1, __ATOMIC_ACQ_REL,
                                       __HIP_MEMORY_SCOPE_AGENT);
                int budget = 256;               // bounded: cannot deadlock
                while (__hip_atomic_load(&phc[ph], __ATOMIC_ACQUIRE,
                                         __HIP_MEMORY_SCOPE_AGENT) < NBLK_C
                       && --budget) {
                    __builtin_amdgcn_s_sleep(8);
                }
            }
            __syncthreads();
        }
    }

    #pragma unroll
    for (int k = 0; k < NSLOT; ++k) {
        const int n = wg + k * NWAVES_C;
        if (n < N_NODES) {
            float ax = accs[wv][k][0][lane];
            float ay = accs[wv][k][1][lane];
            float z  = accs[wv][k][2][lane];
            int cnt = cnt_in[n];
            if (cnt > CAP) {                    // statistically never
                int on = min(*ovf_n, OVF_CAP);
                for (int j = 0; j < on; ++j) {
                    int2 pr = ovf[j];
                    if (pr.x == n) {
                        uint2 p = *(const uint2*)(kv + (((uint)pr.y << 7) + loff));
                        attn_step(p, qx[k], qy[k], ax, ay, z);
                    }
                }
            }
            float inv = 1.0f / (z + 1e-6f);
            float2 o; o.x = ax * inv; o.y = ay * inv;
            *(float2*)(out + ((size_t)n << 7) + (lane << 1)) = o;
        }
    }
}

extern "C" void kernel_launch(void* const* d_in, const int* in_sizes, int n_in,
                              void* d_out, int out_size, void* d_ws, size_t ws_size,
                              hipStream_t stream) {
    const float* h   = (const float*)d_in[0];
    const float* WQ  = (const float*)d_in[1];
    const float* bQ  = (const float*)d_in[2];
    const float* WK  = (const float*)d_in[3];
    const float* bK  = (const float*)d_in[4];
    const float* WV  = (const float*)d_in[5];
    const float* bV  = (const float*)d_in[6];
    const int*   src = (const int*)d_in[7];
    const int*   dst = (const int*)d_in[8];
    float* out = (float*)d_out;
    float* ws  = (float*)d_ws;
    int*   wsi = (int*)d_ws;

    int*   cnt_out = wsi + O_CNTO;
    int*   cnt_in  = wsi + O_CNTI;
    int*   ovf_n   = wsi + O_OVFN;
    int2*  ovf     = (int2*)(wsi + O_OVF);
    int*   bin_cnt = wsi + O_BINC;
    int*   phc     = wsi + O_PHC;
    int*   bucket  = wsi + O_BUCKET;
    int2*  pairs   = (int2*)(wsi + O_PAIRS);
    uint*  hb      = (uint*)(ws + O_HB);
    uint*  aggb    = (uint*)(ws + O_AGGB);
    uint*  wt      = (uint*)(ws + O_WT);
    uint*  qb      = (uint*)(ws + O_QB);
    uint*  kv      = (uint*)(ws + O_KV);

    // zero cnt_out, cnt_in, ovf_n, (ovf), bin_cnt, phase counters in one shot
    hipMemsetAsync(wsi, 0, (O_PHC + NPH) * sizeof(int), stream);

    k_wt<<<(3 * 8192 + 255) / 256, 256, 0, stream>>>(WQ, WK, WV, wt);

    k_part<<<(N_EDGES + EPB - 1) / EPB, 256, 0, stream>>>(src, dst, cnt_out,
                                                          bin_cnt, pairs);
    k_bins<<<NBINS, 256, 0, stream>>>(bin_cnt, pairs, cnt_in, bucket, ovf_n, ovf);

    k_hb<<<(N_NODES * 64 + 255) / 256, 256, 0, stream>>>(h, cnt_out, hb);

    k_agg<<<N_NODES / 4, 256, 0, stream>>>(cnt_in, bucket, ovf_n, ovf, hb, aggb);

    dim3 g_qkv((N_NODES + 127) / 128, 3);
    k_qkv<<<g_qkv, 256, 0, stream>>>(aggb, wt, bQ, bK, bV, qb, kv);

    k_attn_coop<<<NBLK_C, 256, 0, stream>>>(cnt_in, bucket, ovf_n, ovf,
                                            qb, kv, phc, out);
}

// Round 7
// 751.284 us; speedup vs baseline: 4.1146x; 4.1146x over previous
//
#include <hip/hip_runtime.h>

#define N_NODES 50000
#define N_EDGES 1600000
#define CAP 64            // bucket capacity per node; Poisson(32) tail @64 ~ 1e-7
#define OVF_CAP 8192

// Binned build parameters
#define BIN_SHIFT 7
#define BIN_NODES 128               // nodes per bin = 1<<BIN_SHIFT
#define NBINS 391                   // ceil(50000/128)
#define BIN_CAP 5120                // mean 4092, sigma ~64 -> 16 sigma headroom
#define EPB 4096                    // edges per k_part block

// Phase-tiled persistent attention parameters
#define NBLK_C 768                  // 3 blocks/CU x 256 CU -> co-resident
#define NWAVES_C 3072               // NBLK_C * 4 waves
#define NSLOT 17                    // ceil(50000/3072) nodes per wave
#define NPH 8                       // src phases
#define TILE_N 6250                 // src nodes per phase; KV tile = 3.2 MB < 4 MB L2

// Workspace element offsets (4-byte units). Peak ~77.4 MB.
#define O_CNTO   0         // int[50000]  out-degree
#define O_CNTI   50000     // int[50000]  in-degree (also bucket fill)
#define O_OVFN   100000    // int[1]      overflow count
#define O_OVF    100002    // int2[8192]  overflow (dst,src) pairs
#define O_BINC   116400    // int[391]    per-bin edge count (ends 116791)
#define O_PHC    116800    // int[8]      phase barrier counters (ends 116808 < 120000)
#define O_BUCKET 120000    // int[50000*64] src per slot
#define O_HB     3320000   // uint[3.2M]  bf16x2 h*norm_out
#define O_AGGB   6520000   // uint[3.2M]  bf16x2 agg rows (256 B/node)
#define O_WT     9720000   // uint[24576] bf16 W^T for Q,K,V: [3][128 n][64 k-pairs]
#define O_QB     9750000   // uint[3.2M]  bf16x2 Q rows (64 uints/node)
#define O_KV     12950000  // uint[6.4M]  interleaved bf16 K/V rows (512 B/node)
// pairs overlays hb/aggb: written by k_part, dead after k_bins, before k_hb/k_agg write
#define O_PAIRS  3320000   // int2[391*5120] = 16.0 MB, ends at float-ofs 7323840 < O_WT

typedef unsigned int uint;
typedef unsigned long long ulong64;
typedef __attribute__((ext_vector_type(8))) short short8;
typedef __attribute__((ext_vector_type(4))) float floatx4;

union U16 { uint4 u; short8 s; };

__device__ __forceinline__ uint f2bf2(float a, float b) {
    uint ua = __float_as_uint(a); ua = (ua + 0x7fffu + ((ua >> 16) & 1u)) >> 16;
    uint ub = __float_as_uint(b); ub = (ub + 0x7fffu + ((ub >> 16) & 1u)) >> 16;
    return ua | (ub << 16);
}
__device__ __forceinline__ float bflo(uint u) { return __uint_as_float(u << 16); }
__device__ __forceinline__ float bfhi(uint u) { return __uint_as_float(u & 0xffff0000u); }

// DPP cross-lane: VALU-only (no ds_bpermute, no lgkmcnt stalls).
template<int CTRL>
__device__ __forceinline__ float dpp_add8(float x) {
    int t = __builtin_amdgcn_update_dpp(0, __float_as_int(x), CTRL, 0xF, 0xF, true);
    return x + __int_as_float(t);
}
__device__ __forceinline__ float dpp_xor1(float x) {
    int t = __builtin_amdgcn_update_dpp(0, __float_as_int(x), 0xB1, 0xF, 0xF, true);
    return __int_as_float(t);
}

// Phase A: bin edges by dst>>7.
__global__ __launch_bounds__(256) void k_part(const int* __restrict__ src,
                                              const int* __restrict__ dst,
                                              int* cnt_out,
                                              int* bin_cnt,
                                              int2* __restrict__ pairs) {
    __shared__ int hist[NBINS];
    __shared__ int base[NBINS];
    const int t = threadIdx.x;
    const int e0 = blockIdx.x * EPB;

    for (int b = t; b < NBINS; b += 256) hist[b] = 0;
    __syncthreads();

    #pragma unroll
    for (int i = 0; i < EPB / 256; ++i) {
        int e = e0 + i * 256 + t;
        if (e < N_EDGES) {
            int d = dst[e];
            atomicAdd(&hist[d >> BIN_SHIFT], 1);
            atomicAdd(&cnt_out[src[e]], 1);
        }
    }
    __syncthreads();

    for (int b = t; b < NBINS; b += 256) {
        base[b] = atomicAdd(&bin_cnt[b], hist[b]);
        hist[b] = 0;                  // reuse as cursor
    }
    __syncthreads();

    #pragma unroll
    for (int i = 0; i < EPB / 256; ++i) {
        int e = e0 + i * 256 + t;
        if (e < N_EDGES) {
            int d = dst[e], s = src[e];
            int bin = d >> BIN_SHIFT;
            int idx = base[bin] + atomicAdd(&hist[bin], 1);
            if (idx < BIN_CAP)
                pairs[(size_t)bin * BIN_CAP + idx] = make_int2(d, s);
        }
    }
}

// Phase B: one block per bin; LDS-atomic position assignment; then bitonic-sort
// each bucket row by src id (load-bearing: k_attn_coop's cursor logic needs
// ascending rows so each phase's entries are a contiguous prefix range).
__global__ __launch_bounds__(256) void k_bins(const int* __restrict__ bin_cnt,
                                              const int2* __restrict__ pairs,
                                              int* __restrict__ cnt_in,
                                              int* __restrict__ bucket,
                                              int* ovf_n, int2* __restrict__ ovf) {
    __shared__ int lcnt[BIN_NODES];
    const int b = blockIdx.x;
    const int t = threadIdx.x;
    for (int i = t; i < BIN_NODES; i += 256) lcnt[i] = 0;
    __syncthreads();

    const int nb = min(bin_cnt[b], BIN_CAP);
    const int2* pp = pairs + (size_t)b * BIN_CAP;
    for (int i = t; i < nb; i += 256) {
        int2 p = pp[i];                        // p.x = dst, p.y = src
        int pos = atomicAdd(&lcnt[p.x & (BIN_NODES - 1)], 1);
        if (pos < CAP) {
            bucket[((size_t)p.x << 6) + pos] = p.y;
        } else {                               // statistically never; safety net
            int o = atomicAdd(ovf_n, 1);
            if (o < OVF_CAP) ovf[o] = p;
        }
    }
    __syncthreads();

    const int node0 = b << BIN_SHIFT;
    for (int i = t; i < BIN_NODES; i += 256) {
        int n = node0 + i;
        if (n < N_NODES) cnt_in[n] = lcnt[i];  // total count incl. overflow
    }
    __syncthreads();

    // Bitonic sort of each bucket row (64 lanes, 21 compare-exchange steps).
    const int wv = t >> 6, ln = t & 63;
    for (int q = wv; q < BIN_NODES; q += 4) {
        int n = node0 + q;
        if (n >= N_NODES) continue;
        int m = min(lcnt[q], CAP);
        if (m <= 1) continue;
        int* br = bucket + ((size_t)n << 6);
        int v = (ln < m) ? br[ln] : 0x7fffffff;   // sentinel sorts to the top
        #pragma unroll
        for (int k = 2; k <= 64; k <<= 1) {
            #pragma unroll
            for (int j = k >> 1; j > 0; j >>= 1) {
                int p = __shfl_xor(v, j);
                bool keepMin = (((ln & j) == 0) == ((ln & k) == 0));
                v = keepMin ? min(v, p) : max(v, p);
            }
        }
        if (ln < m) br[ln] = v;
    }
}

// W^T cast: wt[y][n][k2] = bf16x2(W_y[2k2][n], W_y[2k2+1][n])
__global__ __launch_bounds__(256) void k_wt(const float* __restrict__ WQ,
                                            const float* __restrict__ WK,
                                            const float* __restrict__ WV,
                                            uint* __restrict__ wt) {
    int idx = blockIdx.x * 256 + threadIdx.x;   // [0, 3*8192)
    if (idx < 3 * 8192) {
        int y = idx >> 13;
        int rem = idx & 8191;
        int k2 = rem >> 7;          // 0..63
        int n  = rem & 127;         // coalesced reads
        const float* W = (y == 0) ? WQ : (y == 1) ? WK : WV;
        float a = W[(2 * k2) * 128 + n];
        float b = W[(2 * k2 + 1) * 128 + n];
        wt[(y << 13) + (n << 6) + k2] = f2bf2(a, b);
    }
}

// hb[n][j] = bf16(h[n][j] * rsqrt(max(deg_out,1)))
__global__ __launch_bounds__(256) void k_hb(const float* __restrict__ h,
                                            const int* __restrict__ cnt_out,
                                            uint* __restrict__ hb) {
    int idx = blockIdx.x * 256 + threadIdx.x;   // [0, N*64)
    if (idx < N_NODES * 64) {
        int n = idx >> 6;
        float no = rsqrtf(fmaxf((float)cnt_out[n], 1.0f));
        float2 hv = *(const float2*)(h + ((size_t)idx << 1));
        hb[idx] = f2bf2(hv.x * no, hv.y * no);
    }
}

// aggb[n] = bf16( rsqrt(max(deg_in,1)) * sum_{slots of n} hb[s] )
__global__ __launch_bounds__(256) void k_agg(
    const int* __restrict__ cnt_in, const int* __restrict__ bucket,
    const int* __restrict__ ovf_n, const int2* __restrict__ ovf,
    const uint* __restrict__ hb, uint* __restrict__ aggb)
{
    int n = blockIdx.x * 4 + (threadIdx.x >> 6);
    int lane = threadIdx.x & 63;
    int cnt = cnt_in[n];
    int m = min(cnt, CAP);
    const int* b = bucket + ((size_t)n << 6);
    int s_own = b[lane];                 // whole bucket row, one coalesced load
    float ax = 0.f, ay = 0.f;

    if (m > 0) {
        uint uA[16], uB[16];
        const int nb = (m + 15) >> 4;
        const int mm1 = m - 1;

#define AGLD(P, base) do { _Pragma("unroll")                                   \
        for (int j = 0; j < 16; ++j) {                                         \
            int sj = __builtin_amdgcn_readlane(s_own, min((base) + j, mm1));   \
            P[j] = hb[((uint)sj << 6) + (uint)lane];                           \
        } } while (0)
#define AGCMP(P, base) do { _Pragma("unroll")                                  \
        for (int j = 0; j < 16; ++j) {                                         \
            if ((base) + j < m) { ax += bflo(P[j]); ay += bfhi(P[j]); }        \
        } } while (0)

        AGLD(uA, 0);
        int t = 0;
        while (t + 1 < nb) {
            AGLD(uB, (t + 1) << 4);
            AGCMP(uA, t << 4);
            ++t;
            if (t + 1 < nb) {
                AGLD(uA, (t + 1) << 4);
                AGCMP(uB, t << 4);
                ++t;
            } else {
                AGCMP(uB, t << 4);
                ++t;
                break;
            }
        }
        if (t < nb) { AGCMP(uA, t << 4); }
#undef AGLD
#undef AGCMP
    }

    if (cnt > CAP) {                       // statistically never; correctness net
        int on = min(*ovf_n, OVF_CAP);
        for (int j = 0; j < on; ++j) {
            int2 p = ovf[j];
            if (p.x == n) {
                uint u = hb[((uint)p.y << 6) + (uint)lane];
                ax += bflo(u);
                ay += bfhi(u);
            }
        }
    }
    float ni = rsqrtf(fmaxf((float)cnt, 1.0f));
    aggb[((size_t)n << 6) + lane] = f2bf2(ax * ni, ay * ni);
}

// Fused QKV projection via bf16 MFMA. grid (391, 3).
__global__ __launch_bounds__(256) void k_qkv(
    const uint* __restrict__ aggb, const uint* __restrict__ wt,
    const float* __restrict__ bQ, const float* __restrict__ bK,
    const float* __restrict__ bV,
    uint* __restrict__ qb, uint* __restrict__ kv)
{
    const int y = blockIdx.y;
    const int row0 = blockIdx.x * 128;
    const float* bias = (y == 0) ? bQ : (y == 1) ? bK : bV;

    __shared__ uint sA[128 * 68];   // A tile, row stride 68 uints

    const int t = threadIdx.x;
    for (int idx = t; idx < 128 * 16; idx += 256) {
        int r = idx >> 4, c4 = (idx & 15) << 2;
        int row = row0 + r;
        uint4 v = make_uint4(0u, 0u, 0u, 0u);
        if (row < N_NODES) v = *(const uint4*)(aggb + ((size_t)row << 6) + c4);
        *(uint4*)(&sA[r * 68 + c4]) = v;
    }
    __syncthreads();

    const int wave = t >> 6;
    const int lane = t & 63;
    const int mrow = lane & 15;     // m (A) / n (B) / col (C)
    const int kq   = lane >> 4;     // 0..3
    const int mbase = wave * 32;
    const uint* wty = wt + (y << 13);

    floatx4 acc[2][8];
    for (int a = 0; a < 2; ++a)
        for (int b = 0; b < 8; ++b)
            acc[a][b] = (floatx4){0.f, 0.f, 0.f, 0.f};

    for (int kc = 0; kc < 128; kc += 32) {
        int koff = (kc >> 1) + (kq << 2);    // uint offset within a row
        short8 afr[2], bfr[8];
        for (int mt = 0; mt < 2; ++mt) {
            U16 u; u.u = *(const uint4*)(&sA[(mbase + mt * 16 + mrow) * 68 + koff]);
            afr[mt] = u.s;
        }
        for (int nt = 0; nt < 8; ++nt) {
            U16 u; u.u = *(const uint4*)(wty + ((nt * 16 + mrow) << 6) + koff);
            bfr[nt] = u.s;
        }
        for (int mt = 0; mt < 2; ++mt)
            for (int nt = 0; nt < 8; ++nt)
                acc[mt][nt] = __builtin_amdgcn_mfma_f32_16x16x32_bf16(
                    afr[mt], bfr[nt], acc[mt][nt], 0, 0, 0);
    }

    if (y == 0) {
        for (int mt = 0; mt < 2; ++mt) {
            int rbase = row0 + mbase + mt * 16 + kq * 4;
            for (int nt = 0; nt < 8; ++nt) {
                int c = nt * 16 + mrow;
                float bv = bias[c];
                for (int r = 0; r < 4; ++r) {
                    float v = fmaxf(acc[mt][nt][r] + bv, 0.f);
                    float pv = dpp_xor1(v);
                    int row = rbase + r;
                    if (((lane & 1) == 0) && row < N_NODES)
                        qb[((size_t)row << 6) + (c >> 1)] = f2bf2(v, pv);
                }
            }
        }
    } else {
        const int vo = (y == 2) ? 1 : 0;
        for (int mt = 0; mt < 2; ++mt) {
            int rbase = row0 + mbase + mt * 16 + kq * 4;
            for (int nt = 0; nt < 8; ++nt) {
                int c = nt * 16 + mrow;    // even for even lanes
                float bv = bias[c];
                for (int r = 0; r < 4; ++r) {
                    float v = fmaxf(acc[mt][nt][r] + bv, 0.f);
                    float pv = dpp_xor1(v);
                    int row = rbase + r;
                    if (((lane & 1) == 0) && row < N_NODES)
                        kv[((size_t)row << 7) + c + vo] = f2bf2(v, pv);
                }
            }
        }
    }
}

// score path: p-scale folded with log2(e); clamp at +/-10*log2(e); raw v_exp_f32.
#define SC_MUL 0.36067376022243085f   // 0.25 * log2(e)
#define SC_CLP 14.426950408889634f    // 10.0 * log2(e)

__device__ __forceinline__ void attn_step(uint2 kvp, float qx, float qy,
                                          float& ax, float& ay, float& zacc) {
    float p = bflo(kvp.x) * qx + bfhi(kvp.x) * qy;
    p = dpp_add8<0xB1>(p);    // + xor1
    p = dpp_add8<0x4E>(p);    // + xor2
    p = dpp_add8<0x141>(p);   // + xor7 (quad-uniform => == xor4)
    float tt = fminf(fmaxf(p * SC_MUL, -SC_CLP), SC_CLP);
    float sc;
    asm("v_exp_f32 %0, %1" : "=v"(sc) : "v"(tt));   // D = 2^S0
    ax += bflo(kvp.y) * sc;
    ay += bfhi(kvp.y) * sc;
    zacc += sc;
}

// Phase-tiled persistent attention, v3.
// NAMED per-slot state (s/qu/cur as scalars via macros -> guaranteed registers,
// r6's arrays went to scratch per rule #20); accumulators in LDS (lane-private,
// no sync); sorted buckets -> per-phase contiguous prefix range per slot
// (ballot/popc, cursor); 8-deep clamped batch loads (r4-proven MLP pattern);
// s_sleep bounded-poll barrier (perf-only, cannot deadlock, replay-safe).

#define SETUP(k)                                                               \
    const int n##k = wg + (k) * NWAVES_C;                                      \
    int s##k = 0x7fffffff;                                                     \
    uint qu##k = 0u;                                                           \
    int cur##k = 0;                                                            \
    accs[wv][k][0][lane] = 0.f;                                                \
    accs[wv][k][1][lane] = 0.f;                                                \
    accs[wv][k][2][lane] = 0.f;                                                \
    if (n##k < N_NODES) {                                                      \
        int m_ = min(cnt_in[n##k], CAP);                                       \
        int sv_ = bucket[((size_t)n##k << 6) + lane];                          \
        if (lane < m_) s##k = sv_;         /* lanes >= m keep sentinel */      \
        qu##k = qb[((size_t)n##k << 6) + lane];                                \
    }

#define PHASE(k)                                                               \
    {                                                                          \
        ulong64 blt_ = __ballot((uint)s##k < hi);                              \
        int e0_ = __popcll(blt_);          /* sorted -> prefix count */        \
        int b0_ = cur##k;                                                      \
        if (e0_ > b0_) {                                                       \
            float qx_ = bflo(qu##k), qy_ = bfhi(qu##k);                        \
            float lax_ = 0.f, lay_ = 0.f, lz_ = 0.f;                           \
            int em1_ = e0_ - 1;                                                \
            for (int c0 = b0_; c0 < e0_; c0 += 8) {                            \
                uint2 P[8];                                                    \
                _Pragma("unroll")                                              \
                for (int j = 0; j < 8; ++j) {                                  \
                    int idx_ = c0 + j; if (idx_ > em1_) idx_ = em1_;           \
                    int sj_ = __builtin_amdgcn_readlane(s##k, idx_);           \
                    P[j] = *(const uint2*)(kv + (((uint)sj_ << 7) + loff));    \
                }                                                              \
                _Pragma("unroll")                                              \
                for (int j = 0; j < 8; ++j)                                    \
                    if (c0 + j < e0_)      /* wave-uniform scalar branch */    \
                        attn_step(P[j], qx_, qy_, lax_, lay_, lz_);            \
            }                                                                  \
            accs[wv][k][0][lane] += lax_;                                      \
            accs[wv][k][1][lane] += lay_;                                      \
            accs[wv][k][2][lane] += lz_;                                       \
            cur##k = e0_;                                                      \
        }                                                                      \
    }

#define FINISH(k)                                                              \
    if (n##k < N_NODES) {                                                      \
        float ax_ = accs[wv][k][0][lane];                                      \
        float ay_ = accs[wv][k][1][lane];                                      \
        float z_  = accs[wv][k][2][lane];                                      \
        int cnt_ = cnt_in[n##k];                                               \
        if (cnt_ > CAP) {                    /* statistically never */         \
            float qx_ = bflo(qu##k), qy_ = bfhi(qu##k);                        \
            int on_ = min(*ovf_n, OVF_CAP);                                    \
            for (int j2 = 0; j2 < on_; ++j2) {                                 \
                int2 pr_ = ovf[j2];                                            \
                if (pr_.x == n##k) {                                           \
                    uint2 p_ = *(const uint2*)(kv + (((uint)pr_.y << 7) + loff)); \
                    attn_step(p_, qx_, qy_, ax_, ay_, z_);                     \
                }                                                              \
            }                                                                  \
        }                                                                      \
        float inv_ = 1.0f / (z_ + 1e-6f);                                      \
        float2 o_; o_.x = ax_ * inv_; o_.y = ay_ * inv_;                       \
        *(float2*)(out + ((size_t)n##k << 7) + (lane << 1)) = o_;              \
    }

__global__ __launch_bounds__(256, 3) void k_attn_coop(
    const int* __restrict__ cnt_in, const int* __restrict__ bucket,
    const int* __restrict__ ovf_n, const int2* __restrict__ ovf,
    const uint* __restrict__ qb, const uint* __restrict__ kv,
    int* phc, float* __restrict__ out)
{
    __shared__ float accs[4][NSLOT][3][64];   // 52224 B; lane-private slices

    const int lane = threadIdx.x & 63;
    const int wv = threadIdx.x >> 6;
    const int wg = blockIdx.x * 4 + wv;
    const uint loff = (uint)(lane << 1);

    SETUP(0)  SETUP(1)  SETUP(2)  SETUP(3)  SETUP(4)  SETUP(5)
    SETUP(6)  SETUP(7)  SETUP(8)  SETUP(9)  SETUP(10) SETUP(11)
    SETUP(12) SETUP(13) SETUP(14) SETUP(15) SETUP(16)

    for (int ph = 0; ph < NPH; ++ph) {
        const uint hi = (uint)((ph + 1) * TILE_N);

        PHASE(0)  PHASE(1)  PHASE(2)  PHASE(3)  PHASE(4)  PHASE(5)
        PHASE(6)  PHASE(7)  PHASE(8)  PHASE(9)  PHASE(10) PHASE(11)
        PHASE(12) PHASE(13) PHASE(14) PHASE(15) PHASE(16)

        if (ph + 1 < NPH) {                     // perf-only temporal barrier
            __syncthreads();
            if (threadIdx.x == 0) {
                __hip_atomic_fetch_add(&phc[ph], 1, __ATOMIC_RELAXED,
                                       __HIP_MEMORY_SCOPE_AGENT);
                int budget = 256;               // bounded: cannot deadlock
                while (__hip_atomic_load(&phc[ph], __ATOMIC_RELAXED,
                                         __HIP_MEMORY_SCOPE_AGENT) < NBLK_C
                       && --budget) {
                    __builtin_amdgcn_s_sleep(8);
                }
            }
            __syncthreads();
        }
    }

    FINISH(0)  FINISH(1)  FINISH(2)  FINISH(3)  FINISH(4)  FINISH(5)
    FINISH(6)  FINISH(7)  FINISH(8)  FINISH(9)  FINISH(10) FINISH(11)
    FINISH(12) FINISH(13) FINISH(14) FINISH(15) FINISH(16)
}

extern "C" void kernel_launch(void* const* d_in, const int* in_sizes, int n_in,
                              void* d_out, int out_size, void* d_ws, size_t ws_size,
                              hipStream_t stream) {
    const float* h   = (const float*)d_in[0];
    const float* WQ  = (const float*)d_in[1];
    const float* bQ  = (const float*)d_in[2];
    const float* WK  = (const float*)d_in[3];
    const float* bK  = (const float*)d_in[4];
    const float* WV  = (const float*)d_in[5];
    const float* bV  = (const float*)d_in[6];
    const int*   src = (const int*)d_in[7];
    const int*   dst = (const int*)d_in[8];
    float* out = (float*)d_out;
    float* ws  = (float*)d_ws;
    int*   wsi = (int*)d_ws;

    int*   cnt_out = wsi + O_CNTO;
    int*   cnt_in  = wsi + O_CNTI;
    int*   ovf_n   = wsi + O_OVFN;
    int2*  ovf     = (int2*)(wsi + O_OVF);
    int*   bin_cnt = wsi + O_BINC;
    int*   phc     = wsi + O_PHC;
    int*   bucket  = wsi + O_BUCKET;
    int2*  pairs   = (int2*)(wsi + O_PAIRS);
    uint*  hb      = (uint*)(ws + O_HB);
    uint*  aggb    = (uint*)(ws + O_AGGB);
    uint*  wt      = (uint*)(ws + O_WT);
    uint*  qb      = (uint*)(ws + O_QB);
    uint*  kv      = (uint*)(ws + O_KV);

    // zero cnt_out, cnt_in, ovf_n, (ovf), bin_cnt, phase counters in one shot
    hipMemsetAsync(wsi, 0, (O_PHC + NPH) * sizeof(int), stream);

    k_wt<<<(3 * 8192 + 255) / 256, 256, 0, stream>>>(WQ, WK, WV, wt);

    k_part<<<(N_EDGES + EPB - 1) / EPB, 256, 0, stream>>>(src, dst, cnt_out,
                                                          bin_cnt, pairs);
    k_bins<<<NBINS, 256, 0, stream>>>(bin_cnt, pairs, cnt_in, bucket, ovf_n, ovf);

    k_hb<<<(N_NODES * 64 + 255) / 256, 256, 0, stream>>>(h, cnt_out, hb);

    k_agg<<<N_NODES / 4, 256, 0, stream>>>(cnt_in, bucket, ovf_n, ovf, hb, aggb);

    dim3 g_qkv((N_NODES + 127) / 128, 3);
    k_qkv<<<g_qkv, 256, 0, stream>>>(aggb, wt, bQ, bK, bV, qb, kv);

    k_attn_coop<<<NBLK_C, 256, 0, stream>>>(cnt_in, bucket, ovf_n, ovf,
                                            qb, kv, phc, out);
}

// Round 8
// 529.146 us; speedup vs baseline: 5.8419x; 1.4198x over previous
//
#include <hip/hip_runtime.h>

#define N_NODES 50000
#define N_EDGES 1600000
#define CAP 64            // bucket capacity per node; Poisson(32) tail @64 ~ 1e-7
#define OVF_CAP 8192

// Binned build parameters
#define BIN_SHIFT 7
#define BIN_NODES 128               // nodes per bin = 1<<BIN_SHIFT
#define NBINS 391                   // ceil(50000/128)
#define BIN_CAP 5120                // mean 4092, sigma ~64 -> 16 sigma headroom
#define EPB 4096                    // edges per k_part block

// Barrier-free phase-tiled persistent gather parameters
#define NSLOT_P 8                   // nodes per wave
#define NBLK_P 1563                 // ceil(50000/(4*8)) blocks -> fully resident
#define NPH 8                       // src phases
#define TILE_N 6250                 // src nodes per phase; KV tile 3.2 MB, hb 1.6 MB

// Workspace element offsets (4-byte units). Peak ~77.4 MB.
#define O_CNTO   0         // int[50000]  out-degree
#define O_CNTI   50000     // int[50000]  in-degree (also bucket fill)
#define O_OVFN   100000    // int[1]      overflow count
#define O_OVF    100002    // int2[8192]  overflow (dst,src) pairs
#define O_BINC   116400    // int[391]    per-bin edge count (ends 116791 < 120000)
#define O_BUCKET 120000    // int[50000*64] src per slot
#define O_HB     3320000   // uint[3.2M]  bf16x2 h*norm_out
#define O_AGGB   6520000   // uint[3.2M]  bf16x2 agg rows (256 B/node)
#define O_WT     9720000   // uint[24576] bf16 W^T for Q,K,V: [3][128 n][64 k-pairs]
#define O_QB     9750000   // uint[3.2M]  bf16x2 Q rows (64 uints/node)
#define O_KV     12950000  // uint[6.4M]  interleaved bf16 K/V rows (512 B/node)
// pairs overlays hb/aggb: written by k_part, dead after k_bins, before k_hb/k_agg write
#define O_PAIRS  3320000   // int2[391*5120] = 16.0 MB, ends at float-ofs 7323840 < O_WT

typedef unsigned int uint;
typedef unsigned long long ulong64;
typedef __attribute__((ext_vector_type(8))) short short8;
typedef __attribute__((ext_vector_type(4))) float floatx4;

union U16 { uint4 u; short8 s; };

__device__ __forceinline__ uint f2bf2(float a, float b) {
    uint ua = __float_as_uint(a); ua = (ua + 0x7fffu + ((ua >> 16) & 1u)) >> 16;
    uint ub = __float_as_uint(b); ub = (ub + 0x7fffu + ((ub >> 16) & 1u)) >> 16;
    return ua | (ub << 16);
}
__device__ __forceinline__ float bflo(uint u) { return __uint_as_float(u << 16); }
__device__ __forceinline__ float bfhi(uint u) { return __uint_as_float(u & 0xffff0000u); }

// DPP cross-lane: VALU-only (no ds_bpermute, no lgkmcnt stalls).
template<int CTRL>
__device__ __forceinline__ float dpp_add8(float x) {
    int t = __builtin_amdgcn_update_dpp(0, __float_as_int(x), CTRL, 0xF, 0xF, true);
    return x + __int_as_float(t);
}
__device__ __forceinline__ float dpp_xor1(float x) {
    int t = __builtin_amdgcn_update_dpp(0, __float_as_int(x), 0xB1, 0xF, 0xF, true);
    return __int_as_float(t);
}

// Phase A: bin edges by dst>>7.
__global__ __launch_bounds__(256) void k_part(const int* __restrict__ src,
                                              const int* __restrict__ dst,
                                              int* cnt_out,
                                              int* bin_cnt,
                                              int2* __restrict__ pairs) {
    __shared__ int hist[NBINS];
    __shared__ int base[NBINS];
    const int t = threadIdx.x;
    const int e0 = blockIdx.x * EPB;

    for (int b = t; b < NBINS; b += 256) hist[b] = 0;
    __syncthreads();

    #pragma unroll
    for (int i = 0; i < EPB / 256; ++i) {
        int e = e0 + i * 256 + t;
        if (e < N_EDGES) {
            int d = dst[e];
            atomicAdd(&hist[d >> BIN_SHIFT], 1);
            atomicAdd(&cnt_out[src[e]], 1);
        }
    }
    __syncthreads();

    for (int b = t; b < NBINS; b += 256) {
        base[b] = atomicAdd(&bin_cnt[b], hist[b]);
        hist[b] = 0;                  // reuse as cursor
    }
    __syncthreads();

    #pragma unroll
    for (int i = 0; i < EPB / 256; ++i) {
        int e = e0 + i * 256 + t;
        if (e < N_EDGES) {
            int d = dst[e], s = src[e];
            int bin = d >> BIN_SHIFT;
            int idx = base[bin] + atomicAdd(&hist[bin], 1);
            if (idx < BIN_CAP)
                pairs[(size_t)bin * BIN_CAP + idx] = make_int2(d, s);
        }
    }
}

// Phase B: one block per bin; LDS-atomic position assignment; then bitonic-sort
// each bucket row by src id (load-bearing: phase ranges need ascending rows).
__global__ __launch_bounds__(256) void k_bins(const int* __restrict__ bin_cnt,
                                              const int2* __restrict__ pairs,
                                              int* __restrict__ cnt_in,
                                              int* __restrict__ bucket,
                                              int* ovf_n, int2* __restrict__ ovf) {
    __shared__ int lcnt[BIN_NODES];
    const int b = blockIdx.x;
    const int t = threadIdx.x;
    for (int i = t; i < BIN_NODES; i += 256) lcnt[i] = 0;
    __syncthreads();

    const int nb = min(bin_cnt[b], BIN_CAP);
    const int2* pp = pairs + (size_t)b * BIN_CAP;
    for (int i = t; i < nb; i += 256) {
        int2 p = pp[i];                        // p.x = dst, p.y = src
        int pos = atomicAdd(&lcnt[p.x & (BIN_NODES - 1)], 1);
        if (pos < CAP) {
            bucket[((size_t)p.x << 6) + pos] = p.y;
        } else {                               // statistically never; safety net
            int o = atomicAdd(ovf_n, 1);
            if (o < OVF_CAP) ovf[o] = p;
        }
    }
    __syncthreads();

    const int node0 = b << BIN_SHIFT;
    for (int i = t; i < BIN_NODES; i += 256) {
        int n = node0 + i;
        if (n < N_NODES) cnt_in[n] = lcnt[i];  // total count incl. overflow
    }
    __syncthreads();

    // Bitonic sort of each bucket row (64 lanes, 21 compare-exchange steps).
    const int wv = t >> 6, ln = t & 63;
    for (int q = wv; q < BIN_NODES; q += 4) {
        int n = node0 + q;
        if (n >= N_NODES) continue;
        int m = min(lcnt[q], CAP);
        if (m <= 1) continue;
        int* br = bucket + ((size_t)n << 6);
        int v = (ln < m) ? br[ln] : 0x7fffffff;   // sentinel sorts to the top
        #pragma unroll
        for (int k = 2; k <= 64; k <<= 1) {
            #pragma unroll
            for (int j = k >> 1; j > 0; j >>= 1) {
                int p = __shfl_xor(v, j);
                bool keepMin = (((ln & j) == 0) == ((ln & k) == 0));
                v = keepMin ? min(v, p) : max(v, p);
            }
        }
        if (ln < m) br[ln] = v;
    }
}

// W^T cast: wt[y][n][k2] = bf16x2(W_y[2k2][n], W_y[2k2+1][n])
__global__ __launch_bounds__(256) void k_wt(const float* __restrict__ WQ,
                                            const float* __restrict__ WK,
                                            const float* __restrict__ WV,
                                            uint* __restrict__ wt) {
    int idx = blockIdx.x * 256 + threadIdx.x;   // [0, 3*8192)
    if (idx < 3 * 8192) {
        int y = idx >> 13;
        int rem = idx & 8191;
        int k2 = rem >> 7;          // 0..63
        int n  = rem & 127;         // coalesced reads
        const float* W = (y == 0) ? WQ : (y == 1) ? WK : WV;
        float a = W[(2 * k2) * 128 + n];
        float b = W[(2 * k2 + 1) * 128 + n];
        wt[(y << 13) + (n << 6) + k2] = f2bf2(a, b);
    }
}

// hb[n][j] = bf16(h[n][j] * rsqrt(max(deg_out,1)))
__global__ __launch_bounds__(256) void k_hb(const float* __restrict__ h,
                                            const int* __restrict__ cnt_out,
                                            uint* __restrict__ hb) {
    int idx = blockIdx.x * 256 + threadIdx.x;   // [0, N*64)
    if (idx < N_NODES * 64) {
        int n = idx >> 6;
        float no = rsqrtf(fmaxf((float)cnt_out[n], 1.0f));
        float2 hv = *(const float2*)(h + ((size_t)idx << 1));
        hb[idx] = f2bf2(hv.x * no, hv.y * no);
    }
}

// ---------- barrier-free phase-tiled persistent aggregation ----------
// Each wave owns 8 contiguous nodes; all waves co-start and sweep src space
// in the same 8-phase order (prefix ranges over sorted buckets) -> natural
// temporal clustering of hb-row reads without any grid sync. Named scalars
// only (rule #20); 8-deep clamped batch loads.

#define AGSET(k)                                                               \
    const int n##k = wg8 + (k);                                                \
    int s##k = 0x7fffffff;                                                     \
    float ax##k = 0.f, ay##k = 0.f;                                            \
    if (n##k < N_NODES) {                                                      \
        int m_ = min(cnt_in[n##k], CAP);                                       \
        int sv_ = bucket[((size_t)n##k << 6) + lane];                          \
        if (lane < m_) s##k = sv_;                                             \
    }

#define AGPH(k)                                                                \
    {                                                                          \
        int b0_ = __popcll(__ballot((uint)s##k < lo));                         \
        int e0_ = __popcll(__ballot((uint)s##k < hi));                         \
        if (e0_ > b0_) {                                                       \
            int em1_ = e0_ - 1;                                                \
            for (int c0 = b0_; c0 < e0_; c0 += 8) {                            \
                uint P[8];                                                     \
                _Pragma("unroll")                                              \
                for (int j = 0; j < 8; ++j) {                                  \
                    int idx_ = c0 + j; if (idx_ > em1_) idx_ = em1_;           \
                    int sj_ = __builtin_amdgcn_readlane(s##k, idx_);           \
                    P[j] = hb[((uint)sj_ << 6) + (uint)lane];                  \
                }                                                              \
                _Pragma("unroll")                                              \
                for (int j = 0; j < 8; ++j)                                    \
                    if (c0 + j < e0_) { ax##k += bflo(P[j]); ay##k += bfhi(P[j]); } \
            }                                                                  \
        }                                                                      \
    }

#define AGFIN(k)                                                               \
    if (n##k < N_NODES) {                                                      \
        int cnt_ = cnt_in[n##k];                                               \
        if (cnt_ > CAP) {                    /* statistically never */         \
            int on_ = min(*ovf_n, OVF_CAP);                                    \
            for (int j2 = 0; j2 < on_; ++j2) {                                 \
                int2 p_ = ovf[j2];                                             \
                if (p_.x == n##k) {                                            \
                    uint u_ = hb[((uint)p_.y << 6) + (uint)lane];              \
                    ax##k += bflo(u_); ay##k += bfhi(u_);                      \
                }                                                              \
            }                                                                  \
        }                                                                      \
        float ni_ = rsqrtf(fmaxf((float)cnt_, 1.0f));                          \
        aggb[((size_t)n##k << 6) + lane] = f2bf2(ax##k * ni_, ay##k * ni_);    \
    }

__global__ __launch_bounds__(256, 6) void k_agg_p(
    const int* __restrict__ cnt_in, const int* __restrict__ bucket,
    const int* __restrict__ ovf_n, const int2* __restrict__ ovf,
    const uint* __restrict__ hb, uint* __restrict__ aggb)
{
    const int lane = threadIdx.x & 63;
    const int wg8 = (blockIdx.x * 4 + (threadIdx.x >> 6)) * NSLOT_P;

    AGSET(0) AGSET(1) AGSET(2) AGSET(3) AGSET(4) AGSET(5) AGSET(6) AGSET(7)

    for (int ph = 0; ph < NPH; ++ph) {
        const uint lo = (uint)(ph * TILE_N);
        const uint hi = lo + TILE_N;
        AGPH(0) AGPH(1) AGPH(2) AGPH(3) AGPH(4) AGPH(5) AGPH(6) AGPH(7)
        __syncthreads();               // intra-block only: keeps 4 waves L1-coherent
    }

    AGFIN(0) AGFIN(1) AGFIN(2) AGFIN(3) AGFIN(4) AGFIN(5) AGFIN(6) AGFIN(7)
}

// Fused QKV projection via bf16 MFMA. grid (391, 3).
__global__ __launch_bounds__(256) void k_qkv(
    const uint* __restrict__ aggb, const uint* __restrict__ wt,
    const float* __restrict__ bQ, const float* __restrict__ bK,
    const float* __restrict__ bV,
    uint* __restrict__ qb, uint* __restrict__ kv)
{
    const int y = blockIdx.y;
    const int row0 = blockIdx.x * 128;
    const float* bias = (y == 0) ? bQ : (y == 1) ? bK : bV;

    __shared__ uint sA[128 * 68];   // A tile, row stride 68 uints

    const int t = threadIdx.x;
    for (int idx = t; idx < 128 * 16; idx += 256) {
        int r = idx >> 4, c4 = (idx & 15) << 2;
        int row = row0 + r;
        uint4 v = make_uint4(0u, 0u, 0u, 0u);
        if (row < N_NODES) v = *(const uint4*)(aggb + ((size_t)row << 6) + c4);
        *(uint4*)(&sA[r * 68 + c4]) = v;
    }
    __syncthreads();

    const int wave = t >> 6;
    const int lane = t & 63;
    const int mrow = lane & 15;     // m (A) / n (B) / col (C)
    const int kq   = lane >> 4;     // 0..3
    const int mbase = wave * 32;
    const uint* wty = wt + (y << 13);

    floatx4 acc[2][8];
    for (int a = 0; a < 2; ++a)
        for (int b = 0; b < 8; ++b)
            acc[a][b] = (floatx4){0.f, 0.f, 0.f, 0.f};

    for (int kc = 0; kc < 128; kc += 32) {
        int koff = (kc >> 1) + (kq << 2);    // uint offset within a row
        short8 afr[2], bfr[8];
        for (int mt = 0; mt < 2; ++mt) {
            U16 u; u.u = *(const uint4*)(&sA[(mbase + mt * 16 + mrow) * 68 + koff]);
            afr[mt] = u.s;
        }
        for (int nt = 0; nt < 8; ++nt) {
            U16 u; u.u = *(const uint4*)(wty + ((nt * 16 + mrow) << 6) + koff);
            bfr[nt] = u.s;
        }
        for (int mt = 0; mt < 2; ++mt)
            for (int nt = 0; nt < 8; ++nt)
                acc[mt][nt] = __builtin_amdgcn_mfma_f32_16x16x32_bf16(
                    afr[mt], bfr[nt], acc[mt][nt], 0, 0, 0);
    }

    if (y == 0) {
        for (int mt = 0; mt < 2; ++mt) {
            int rbase = row0 + mbase + mt * 16 + kq * 4;
            for (int nt = 0; nt < 8; ++nt) {
                int c = nt * 16 + mrow;
                float bv = bias[c];
                for (int r = 0; r < 4; ++r) {
                    float v = fmaxf(acc[mt][nt][r] + bv, 0.f);
                    float pv = dpp_xor1(v);
                    int row = rbase + r;
                    if (((lane & 1) == 0) && row < N_NODES)
                        qb[((size_t)row << 6) + (c >> 1)] = f2bf2(v, pv);
                }
            }
        }
    } else {
        const int vo = (y == 2) ? 1 : 0;
        for (int mt = 0; mt < 2; ++mt) {
            int rbase = row0 + mbase + mt * 16 + kq * 4;
            for (int nt = 0; nt < 8; ++nt) {
                int c = nt * 16 + mrow;    // even for even lanes
                float bv = bias[c];
                for (int r = 0; r < 4; ++r) {
                    float v = fmaxf(acc[mt][nt][r] + bv, 0.f);
                    float pv = dpp_xor1(v);
                    int row = rbase + r;
                    if (((lane & 1) == 0) && row < N_NODES)
                        kv[((size_t)row << 7) + c + vo] = f2bf2(v, pv);
                }
            }
        }
    }
}

// score path: p-scale folded with log2(e); clamp at +/-10*log2(e); raw v_exp_f32.
#define SC_MUL 0.36067376022243085f   // 0.25 * log2(e)
#define SC_CLP 14.426950408889634f    // 10.0 * log2(e)

__device__ __forceinline__ void attn_step(uint2 kvp, float qx, float qy,
                                          float& ax, float& ay, float& zacc) {
    float p = bflo(kvp.x) * qx + bfhi(kvp.x) * qy;
    p = dpp_add8<0xB1>(p);    // + xor1
    p = dpp_add8<0x4E>(p);    // + xor2
    p = dpp_add8<0x141>(p);   // + xor7 (quad-uniform => == xor4)
    float tt = fminf(fmaxf(p * SC_MUL, -SC_CLP), SC_CLP);
    float sc;
    asm("v_exp_f32 %0, %1" : "=v"(sc) : "v"(tt));   // D = 2^S0
    ax += bflo(kvp.y) * sc;
    ay += bfhi(kvp.y) * sc;
    zacc += sc;
}

// ---------- barrier-free phase-tiled persistent attention ----------

#define ASET(k)                                                                \
    const int n##k = wg8 + (k);                                                \
    int s##k = 0x7fffffff;                                                     \
    uint qu##k = 0u;                                                           \
    float ax##k = 0.f, ay##k = 0.f, z##k = 0.f;                                \
    if (n##k < N_NODES) {                                                      \
        int m_ = min(cnt_in[n##k], CAP);                                       \
        int sv_ = bucket[((size_t)n##k << 6) + lane];                          \
        if (lane < m_) s##k = sv_;         /* lanes >= m keep sentinel */      \
        qu##k = qb[((size_t)n##k << 6) + lane];                                \
    }

#define APH(k)                                                                 \
    {                                                                          \
        int b0_ = __popcll(__ballot((uint)s##k < lo));                         \
        int e0_ = __popcll(__ballot((uint)s##k < hi));                         \
        if (e0_ > b0_) {                                                       \
            float qx_ = bflo(qu##k), qy_ = bfhi(qu##k);                        \
            int em1_ = e0_ - 1;                                                \
            for (int c0 = b0_; c0 < e0_; c0 += 8) {                            \
                uint2 P[8];                                                    \
                _Pragma("unroll")                                              \
                for (int j = 0; j < 8; ++j) {                                  \
                    int idx_ = c0 + j; if (idx_ > em1_) idx_ = em1_;           \
                    int sj_ = __builtin_amdgcn_readlane(s##k, idx_);           \
                    P[j] = *(const uint2*)(kv + (((uint)sj_ << 7) + loff));    \
                }                                                              \
                _Pragma("unroll")                                              \
                for (int j = 0; j < 8; ++j)                                    \
                    if (c0 + j < e0_)      /* wave-uniform scalar branch */    \
                        attn_step(P[j], qx_, qy_, ax##k, ay##k, z##k);         \
            }                                                                  \
        }                                                                      \
    }

#define AFIN(k)                                                                \
    if (n##k < N_NODES) {                                                      \
        int cnt_ = cnt_in[n##k];                                               \
        if (cnt_ > CAP) {                    /* statistically never */         \
            float qx_ = bflo(qu##k), qy_ = bfhi(qu##k);                        \
            int on_ = min(*ovf_n, OVF_CAP);                                    \
            for (int j2 = 0; j2 < on_; ++j2) {                                 \
                int2 pr_ = ovf[j2];                                            \
                if (pr_.x == n##k) {                                           \
                    uint2 p_ = *(const uint2*)(kv + (((uint)pr_.y << 7) + loff)); \
                    attn_step(p_, qx_, qy_, ax##k, ay##k, z##k);               \
                }                                                              \
            }                                                                  \
        }                                                                      \
        float inv_ = 1.0f / (z##k + 1e-6f);                                    \
        float2 o_; o_.x = ax##k * inv_; o_.y = ay##k * inv_;                   \
        *(float2*)(out + ((size_t)n##k << 7) + (lane << 1)) = o_;              \
    }

__global__ __launch_bounds__(256, 5) void k_attn_p(
    const int* __restrict__ cnt_in, const int* __restrict__ bucket,
    const int* __restrict__ ovf_n, const int2* __restrict__ ovf,
    const uint* __restrict__ qb, const uint* __restrict__ kv,
    float* __restrict__ out)
{
    const int lane = threadIdx.x & 63;
    const int wg8 = (blockIdx.x * 4 + (threadIdx.x >> 6)) * NSLOT_P;
    const uint loff = (uint)(lane << 1);

    ASET(0) ASET(1) ASET(2) ASET(3) ASET(4) ASET(5) ASET(6) ASET(7)

    for (int ph = 0; ph < NPH; ++ph) {
        const uint lo = (uint)(ph * TILE_N);
        const uint hi = lo + TILE_N;
        APH(0) APH(1) APH(2) APH(3) APH(4) APH(5) APH(6) APH(7)
        __syncthreads();               // intra-block only: keeps 4 waves L1-coherent
    }

    AFIN(0) AFIN(1) AFIN(2) AFIN(3) AFIN(4) AFIN(5) AFIN(6) AFIN(7)
}

extern "C" void kernel_launch(void* const* d_in, const int* in_sizes, int n_in,
                              void* d_out, int out_size, void* d_ws, size_t ws_size,
                              hipStream_t stream) {
    const float* h   = (const float*)d_in[0];
    const float* WQ  = (const float*)d_in[1];
    const float* bQ  = (const float*)d_in[2];
    const float* WK  = (const float*)d_in[3];
    const float* bK  = (const float*)d_in[4];
    const float* WV  = (const float*)d_in[5];
    const float* bV  = (const float*)d_in[6];
    const int*   src = (const int*)d_in[7];
    const int*   dst = (const int*)d_in[8];
    float* out = (float*)d_out;
    float* ws  = (float*)d_ws;
    int*   wsi = (int*)d_ws;

    int*   cnt_out = wsi + O_CNTO;
    int*   cnt_in  = wsi + O_CNTI;
    int*   ovf_n   = wsi + O_OVFN;
    int2*  ovf     = (int2*)(wsi + O_OVF);
    int*   bin_cnt = wsi + O_BINC;
    int*   bucket  = wsi + O_BUCKET;
    int2*  pairs   = (int2*)(wsi + O_PAIRS);
    uint*  hb      = (uint*)(ws + O_HB);
    uint*  aggb    = (uint*)(ws + O_AGGB);
    uint*  wt      = (uint*)(ws + O_WT);
    uint*  qb      = (uint*)(ws + O_QB);
    uint*  kv      = (uint*)(ws + O_KV);

    // zero cnt_out, cnt_in, ovf_n, (ovf), bin_cnt in one shot
    hipMemsetAsync(wsi, 0, (O_BINC + NBINS) * sizeof(int), stream);

    k_wt<<<(3 * 8192 + 255) / 256, 256, 0, stream>>>(WQ, WK, WV, wt);

    k_part<<<(N_EDGES + EPB - 1) / EPB, 256, 0, stream>>>(src, dst, cnt_out,
                                                          bin_cnt, pairs);
    k_bins<<<NBINS, 256, 0, stream>>>(bin_cnt, pairs, cnt_in, bucket, ovf_n, ovf);

    k_hb<<<(N_NODES * 64 + 255) / 256, 256, 0, stream>>>(h, cnt_out, hb);

    k_agg_p<<<NBLK_P, 256, 0, stream>>>(cnt_in, bucket, ovf_n, ovf, hb, aggb);

    dim3 g_qkv((N_NODES + 127) / 128, 3);
    k_qkv<<<g_qkv, 256, 0, stream>>>(aggb, wt, bQ, bK, bV, qb, kv);

    k_attn_p<<<NBLK_P, 256, 0, stream>>>(cnt_in, bucket, ovf_n, ovf,
                                         qb, kv, out);
}

// Round 9
// 427.857 us; speedup vs baseline: 7.2249x; 1.2367x over previous
//
#include <hip/hip_runtime.h>

#define N_NODES 50000
#define N_EDGES 1600000
#define CAP 64            // bucket capacity per node; Poisson(32) tail @64 ~ 1e-7
#define OVF_CAP 8192

// Binned build parameters
#define BIN_SHIFT 7
#define BIN_NODES 128               // nodes per bin = 1<<BIN_SHIFT
#define NBINS 391                   // ceil(50000/128)
#define BIN_CAP 5120                // mean 4092, sigma ~64 -> 16 sigma headroom
#define EPB 4096                    // edges per k_part block

// Workspace element offsets (4-byte units). Peak ~77.4 MB.
#define O_CNTO   0         // int[50000]  out-degree
#define O_CNTI   50000     // int[50000]  in-degree (also bucket fill)
#define O_OVFN   100000    // int[1]      overflow count
#define O_OVF    100002    // int2[8192]  overflow (dst,src) pairs
#define O_BINC   116400    // int[391]    per-bin edge count (ends 116791 < 120000)
#define O_BUCKET 120000    // int[50000*64] src per slot
#define O_HB     3320000   // uint[3.2M]  bf16x2 h*norm_out
#define O_AGGB   6520000   // uint[3.2M]  bf16x2 agg rows (256 B/node)
#define O_WT     9720000   // uint[24576] bf16 W^T for Q,K,V: [3][128 n][64 k-pairs]
#define O_QB     9750000   // uint[3.2M]  bf16x2 Q rows (64 uints/node)
#define O_KB     12950000  // uint[3.2M]  bf16x2 K rows (256 B/node) -- split, 12.8 MB set
#define O_VB     16150000  // uint[3.2M]  bf16x2 V rows (256 B/node) -- split, 12.8 MB set
// pairs overlays hb/aggb: written by k_part, dead after k_bins, before k_hb/k_agg write
#define O_PAIRS  3320000   // int2[391*5120] = 16.0 MB, ends at float-ofs 7323840 < O_WT

typedef unsigned int uint;
typedef unsigned long long ulong64;
typedef __attribute__((ext_vector_type(8))) short short8;
typedef __attribute__((ext_vector_type(4))) float floatx4;

union U16 { uint4 u; short8 s; };

__device__ __forceinline__ uint f2bf2(float a, float b) {
    uint ua = __float_as_uint(a); ua = (ua + 0x7fffu + ((ua >> 16) & 1u)) >> 16;
    uint ub = __float_as_uint(b); ub = (ub + 0x7fffu + ((ub >> 16) & 1u)) >> 16;
    return ua | (ub << 16);
}
__device__ __forceinline__ float bflo(uint u) { return __uint_as_float(u << 16); }
__device__ __forceinline__ float bfhi(uint u) { return __uint_as_float(u & 0xffff0000u); }

// DPP cross-lane: VALU-only (no ds_bpermute, no lgkmcnt stalls).
// 0xB1 = quad_perm xor1; 0x4E = quad_perm xor2; 0x141 = row_half_mirror
// (mirror within 8 == xor7; after xor1+xor2 quads are uniform => full 8-sum).
template<int CTRL>
__device__ __forceinline__ float dpp_add8(float x) {
    int t = __builtin_amdgcn_update_dpp(0, __float_as_int(x), CTRL, 0xF, 0xF, true);
    return x + __int_as_float(t);
}
__device__ __forceinline__ float dpp_xor1(float x) {
    int t = __builtin_amdgcn_update_dpp(0, __float_as_int(x), 0xB1, 0xF, 0xF, true);
    return __int_as_float(t);
}

// Phase A: bin edges by dst>>7. LDS histogram -> chunked global reservation ->
// scatter (dst,src) pairs into per-bin arrays.
__global__ __launch_bounds__(256) void k_part(const int* __restrict__ src,
                                              const int* __restrict__ dst,
                                              int* cnt_out,
                                              int* bin_cnt,
                                              int2* __restrict__ pairs) {
    __shared__ int hist[NBINS];
    __shared__ int base[NBINS];
    const int t = threadIdx.x;
    const int e0 = blockIdx.x * EPB;

    for (int b = t; b < NBINS; b += 256) hist[b] = 0;
    __syncthreads();

    #pragma unroll
    for (int i = 0; i < EPB / 256; ++i) {
        int e = e0 + i * 256 + t;
        if (e < N_EDGES) {
            int d = dst[e];
            atomicAdd(&hist[d >> BIN_SHIFT], 1);
            atomicAdd(&cnt_out[src[e]], 1);
        }
    }
    __syncthreads();

    for (int b = t; b < NBINS; b += 256) {
        base[b] = atomicAdd(&bin_cnt[b], hist[b]);
        hist[b] = 0;                  // reuse as cursor
    }
    __syncthreads();

    #pragma unroll
    for (int i = 0; i < EPB / 256; ++i) {
        int e = e0 + i * 256 + t;
        if (e < N_EDGES) {
            int d = dst[e], s = src[e];
            int bin = d >> BIN_SHIFT;
            int idx = base[bin] + atomicAdd(&hist[bin], 1);
            if (idx < BIN_CAP)
                pairs[(size_t)bin * BIN_CAP + idx] = make_int2(d, s);
        }
    }
}

// Phase B: one block per bin; LDS-atomic position assignment; bucket writes
// confined to a 32 KB region -> L2 lines fill before eviction.
__global__ __launch_bounds__(256) void k_bins(const int* __restrict__ bin_cnt,
                                              const int2* __restrict__ pairs,
                                              int* __restrict__ cnt_in,
                                              int* __restrict__ bucket,
                                              int* ovf_n, int2* __restrict__ ovf) {
    __shared__ int lcnt[BIN_NODES];
    const int b = blockIdx.x;
    const int t = threadIdx.x;
    for (int i = t; i < BIN_NODES; i += 256) lcnt[i] = 0;
    __syncthreads();

    const int nb = min(bin_cnt[b], BIN_CAP);
    const int2* pp = pairs + (size_t)b * BIN_CAP;
    for (int i = t; i < nb; i += 256) {
        int2 p = pp[i];                        // p.x = dst, p.y = src
        int pos = atomicAdd(&lcnt[p.x & (BIN_NODES - 1)], 1);
        if (pos < CAP) {
            bucket[((size_t)p.x << 6) + pos] = p.y;
        } else {                               // statistically never; safety net
            int o = atomicAdd(ovf_n, 1);
            if (o < OVF_CAP) ovf[o] = p;
        }
    }
    __syncthreads();

    const int node0 = b << BIN_SHIFT;
    for (int i = t; i < BIN_NODES; i += 256) {
        int n = node0 + i;
        if (n < N_NODES) cnt_in[n] = lcnt[i];  // total count incl. overflow
    }
}

// W^T cast: wt[y][n][k2] = bf16x2(W_y[2k2][n], W_y[2k2+1][n])
__global__ __launch_bounds__(256) void k_wt(const float* __restrict__ WQ,
                                            const float* __restrict__ WK,
                                            const float* __restrict__ WV,
                                            uint* __restrict__ wt) {
    int idx = blockIdx.x * 256 + threadIdx.x;   // [0, 3*8192)
    if (idx < 3 * 8192) {
        int y = idx >> 13;
        int rem = idx & 8191;
        int k2 = rem >> 7;          // 0..63
        int n  = rem & 127;         // coalesced reads
        const float* W = (y == 0) ? WQ : (y == 1) ? WK : WV;
        float a = W[(2 * k2) * 128 + n];
        float b = W[(2 * k2 + 1) * 128 + n];
        wt[(y << 13) + (n << 6) + k2] = f2bf2(a, b);
    }
}

// hb[n][j] = bf16(h[n][j] * rsqrt(max(deg_out,1)))
__global__ __launch_bounds__(256) void k_hb(const float* __restrict__ h,
                                            const int* __restrict__ cnt_out,
                                            uint* __restrict__ hb) {
    int idx = blockIdx.x * 256 + threadIdx.x;   // [0, N*64)
    if (idx < N_NODES * 64) {
        int n = idx >> 6;
        float no = rsqrtf(fmaxf((float)cnt_out[n], 1.0f));
        float2 hv = *(const float2*)(h + ((size_t)idx << 1));
        hb[idx] = f2bf2(hv.x * no, hv.y * no);
    }
}

// aggb[n] = bf16( rsqrt(max(deg_in,1)) * sum_{slots of n} hb[s] )
// Bucket row in-lane; readlane indices; 16-wide double-buffered row loads.
__global__ __launch_bounds__(256) void k_agg(
    const int* __restrict__ cnt_in, const int* __restrict__ bucket,
    const int* __restrict__ ovf_n, const int2* __restrict__ ovf,
    const uint* __restrict__ hb, uint* __restrict__ aggb)
{
    int n = blockIdx.x * 4 + (threadIdx.x >> 6);
    int lane = threadIdx.x & 63;
    int cnt = cnt_in[n];
    int m = min(cnt, CAP);
    const int* b = bucket + ((size_t)n << 6);
    int s_own = b[lane];                 // whole bucket row, one coalesced load
    float ax = 0.f, ay = 0.f;

    if (m > 0) {
        uint uA[16], uB[16];
        const int nb = (m + 15) >> 4;
        const int mm1 = m - 1;

#define AGLD(P, base) do { _Pragma("unroll")                                   \
        for (int j = 0; j < 16; ++j) {                                         \
            int sj = __builtin_amdgcn_readlane(s_own, min((base) + j, mm1));   \
            P[j] = hb[((uint)sj << 6) + (uint)lane];                           \
        } } while (0)
#define AGCMP(P, base) do { _Pragma("unroll")                                  \
        for (int j = 0; j < 16; ++j) {                                         \
            if ((base) + j < m) { ax += bflo(P[j]); ay += bfhi(P[j]); }        \
        } } while (0)

        AGLD(uA, 0);
        int t = 0;
        while (t + 1 < nb) {
            AGLD(uB, (t + 1) << 4);
            AGCMP(uA, t << 4);
            ++t;
            if (t + 1 < nb) {
                AGLD(uA, (t + 1) << 4);
                AGCMP(uB, t << 4);
                ++t;
            } else {
                AGCMP(uB, t << 4);
                ++t;
                break;
            }
        }
        if (t < nb) { AGCMP(uA, t << 4); }
#undef AGLD
#undef AGCMP
    }

    if (cnt > CAP) {                       // statistically never; correctness net
        int on = min(*ovf_n, OVF_CAP);
        for (int j = 0; j < on; ++j) {
            int2 p = ovf[j];
            if (p.x == n) {
                uint u = hb[((uint)p.y << 6) + (uint)lane];
                ax += bflo(u);
                ay += bfhi(u);
            }
        }
    }
    float ni = rsqrtf(fmaxf((float)cnt, 1.0f));
    aggb[((size_t)n << 6) + lane] = f2bf2(ax * ni, ay * ni);
}

// Fused QKV projection via bf16 MFMA. grid (391, 3): y selects output
// (qb / kb / vb); all three share the identical packed-row epilogue.
__global__ __launch_bounds__(256) void k_qkv(
    const uint* __restrict__ aggb, const uint* __restrict__ wt,
    const float* __restrict__ bQ, const float* __restrict__ bK,
    const float* __restrict__ bV,
    uint* __restrict__ qb, uint* __restrict__ kb, uint* __restrict__ vb)
{
    const int y = blockIdx.y;
    const int row0 = blockIdx.x * 128;
    const float* bias = (y == 0) ? bQ : (y == 1) ? bK : bV;
    uint* ob = (y == 0) ? qb : (y == 1) ? kb : vb;

    __shared__ uint sA[128 * 68];   // A tile, row stride 68 uints

    const int t = threadIdx.x;
    for (int idx = t; idx < 128 * 16; idx += 256) {
        int r = idx >> 4, c4 = (idx & 15) << 2;
        int row = row0 + r;
        uint4 v = make_uint4(0u, 0u, 0u, 0u);
        if (row < N_NODES) v = *(const uint4*)(aggb + ((size_t)row << 6) + c4);
        *(uint4*)(&sA[r * 68 + c4]) = v;
    }
    __syncthreads();

    const int wave = t >> 6;
    const int lane = t & 63;
    const int mrow = lane & 15;     // m (A) / n (B) / col (C)
    const int kq   = lane >> 4;     // 0..3
    const int mbase = wave * 32;
    const uint* wty = wt + (y << 13);

    floatx4 acc[2][8];
    for (int a = 0; a < 2; ++a)
        for (int b = 0; b < 8; ++b)
            acc[a][b] = (floatx4){0.f, 0.f, 0.f, 0.f};

    for (int kc = 0; kc < 128; kc += 32) {
        int koff = (kc >> 1) + (kq << 2);    // uint offset within a row
        short8 afr[2], bfr[8];
        for (int mt = 0; mt < 2; ++mt) {
            U16 u; u.u = *(const uint4*)(&sA[(mbase + mt * 16 + mrow) * 68 + koff]);
            afr[mt] = u.s;
        }
        for (int nt = 0; nt < 8; ++nt) {
            U16 u; u.u = *(const uint4*)(wty + ((nt * 16 + mrow) << 6) + koff);
            bfr[nt] = u.s;
        }
        for (int mt = 0; mt < 2; ++mt)
            for (int nt = 0; nt < 8; ++nt)
                acc[mt][nt] = __builtin_amdgcn_mfma_f32_16x16x32_bf16(
                    afr[mt], bfr[nt], acc[mt][nt], 0, 0, 0);
    }

    // C/D: col = lane&15 (= mrow), row = kq*4 + reg. Pack pairs via DPP xor1.
    for (int mt = 0; mt < 2; ++mt) {
        int rbase = row0 + mbase + mt * 16 + kq * 4;
        for (int nt = 0; nt < 8; ++nt) {
            int c = nt * 16 + mrow;
            float bv = bias[c];
            for (int r = 0; r < 4; ++r) {
                float v = fmaxf(acc[mt][nt][r] + bv, 0.f);
                float pv = dpp_xor1(v);
                int row = rbase + r;
                if (((lane & 1) == 0) && row < N_NODES)
                    ob[((size_t)row << 6) + (c >> 1)] = f2bf2(v, pv);
            }
        }
    }
}

// score path: p-scale folded with log2(e); clamp at +/-10*log2(e); raw v_exp_f32.
#define SC_MUL 0.36067376022243085f   // 0.25 * log2(e)
#define SC_CLP 14.426950408889634f    // 10.0 * log2(e)

// Split-KV attention: pass 1 gathers K rows (256 B/edge from a 12.8 MB set),
// computes per-head scores via DPP reduce, stashes them in wave-private LDS
// and accumulates z; pass 2 gathers V rows (256 B/edge, separate 12.8 MB set)
// weighted by the stashed scores. Halving the random working set per pass
// raises the per-XCD L2 hit rate vs the interleaved 25.6 MB layout.
// Both passes: bucket row in-lane + readlane indices, 8-deep ping-pong loads.
__global__ __launch_bounds__(256) void k_attn(
    const int* __restrict__ cnt_in, const int* __restrict__ bucket,
    const int* __restrict__ ovf_n, const int2* __restrict__ ovf,
    const uint* __restrict__ qb, const uint* __restrict__ kb,
    const uint* __restrict__ vb, float* __restrict__ out)
{
    __shared__ float sc_lds[4][CAP][8];   // 8 KB: per-wave scores[edge][head]

    const int wv = threadIdx.x >> 6;
    const int n = blockIdx.x * 4 + wv;
    const int lane = threadIdx.x & 63;
    int cnt = cnt_in[n];
    int m = min(cnt, CAP);
    const int* b = bucket + ((size_t)n << 6);
    int s_own = b[lane];                 // whole bucket row, one coalesced load

    uint qu = qb[((size_t)n << 6) + lane];
    float qx = bflo(qu), qy = bfhi(qu);
    float ax = 0.f, ay = 0.f, zacc = 0.f;
    const int head = lane >> 3;

    if (m > 0) {
        const int nb = (m + 7) >> 3;
        const int mm1 = m - 1;
        uint pA[8], pB[8];

        // ---------- pass 1: scores + z (K gather) ----------
#define KLD(P, base) do { _Pragma("unroll")                                    \
        for (int j = 0; j < 8; ++j) {                                          \
            int sj = __builtin_amdgcn_readlane(s_own, min((base) + j, mm1));   \
            P[j] = kb[((uint)sj << 6) + (uint)lane];                           \
        } } while (0)
#define KCMP(P, base) do { _Pragma("unroll")                                   \
        for (int j = 0; j < 8; ++j) {                                          \
            if ((base) + j < m) {                                              \
                float p_ = bflo(P[j]) * qx + bfhi(P[j]) * qy;                  \
                p_ = dpp_add8<0xB1>(p_);                                       \
                p_ = dpp_add8<0x4E>(p_);                                       \
                p_ = dpp_add8<0x141>(p_);                                      \
                float tt_ = fminf(fmaxf(p_ * SC_MUL, -SC_CLP), SC_CLP);        \
                float sc_;                                                     \
                asm("v_exp_f32 %0, %1" : "=v"(sc_) : "v"(tt_));                \
                zacc += sc_;                                                   \
                if ((lane & 7) == 0) sc_lds[wv][(base) + j][head] = sc_;       \
            }                                                                  \
        } } while (0)

        KLD(pA, 0);
        int t = 0;
        while (t + 1 < nb) {
            KLD(pB, (t + 1) << 3);
            KCMP(pA, t << 3);
            ++t;
            if (t + 1 < nb) {
                KLD(pA, (t + 1) << 3);
                KCMP(pB, t << 3);
                ++t;
            } else {
                KCMP(pB, t << 3);
                ++t;
                break;
            }
        }
        if (t < nb) { KCMP(pA, t << 3); }
#undef KLD
#undef KCMP

        // same-wave LDS write->read: compiler inserts lgkmcnt wait on first read

        // ---------- pass 2: weighted V ----------
#define VLD(P, base) do { _Pragma("unroll")                                    \
        for (int j = 0; j < 8; ++j) {                                          \
            int sj = __builtin_amdgcn_readlane(s_own, min((base) + j, mm1));   \
            P[j] = vb[((uint)sj << 6) + (uint)lane];                           \
        } } while (0)
#define VCMP(P, base) do { _Pragma("unroll")                                   \
        for (int j = 0; j < 8; ++j) {                                          \
            if ((base) + j < m) {                                              \
                float sc_ = sc_lds[wv][(base) + j][head];                      \
                ax += bflo(P[j]) * sc_;                                        \
                ay += bfhi(P[j]) * sc_;                                        \
            }                                                                  \
        } } while (0)

        VLD(pA, 0);
        t = 0;
        while (t + 1 < nb) {
            VLD(pB, (t + 1) << 3);
            VCMP(pA, t << 3);
            ++t;
            if (t + 1 < nb) {
                VLD(pA, (t + 1) << 3);
                VCMP(pB, t << 3);
                ++t;
            } else {
                VCMP(pB, t << 3);
                ++t;
                break;
            }
        }
        if (t < nb) { VCMP(pA, t << 3); }
#undef VLD
#undef VCMP
    }

    if (cnt > CAP) {                       // statistically never; correctness net
        int on = min(*ovf_n, OVF_CAP);
        for (int j = 0; j < on; ++j) {
            int2 pr = ovf[j];
            if (pr.x == n) {
                uint kk = kb[((uint)pr.y << 6) + (uint)lane];
                uint vvv = vb[((uint)pr.y << 6) + (uint)lane];
                float p = bflo(kk) * qx + bfhi(kk) * qy;
                p = dpp_add8<0xB1>(p);
                p = dpp_add8<0x4E>(p);
                p = dpp_add8<0x141>(p);
                float tt = fminf(fmaxf(p * SC_MUL, -SC_CLP), SC_CLP);
                float sc;
                asm("v_exp_f32 %0, %1" : "=v"(sc) : "v"(tt));
                zacc += sc;
                ax += bflo(vvv) * sc;
                ay += bfhi(vvv) * sc;
            }
        }
    }

    float inv = 1.0f / (zacc + 1e-6f);
    float2 o; o.x = ax * inv; o.y = ay * inv;
    *(float2*)(out + ((size_t)n << 7) + (lane << 1)) = o;
}

extern "C" void kernel_launch(void* const* d_in, const int* in_sizes, int n_in,
                              void* d_out, int out_size, void* d_ws, size_t ws_size,
                              hipStream_t stream) {
    const float* h   = (const float*)d_in[0];
    const float* WQ  = (const float*)d_in[1];
    const float* bQ  = (const float*)d_in[2];
    const float* WK  = (const float*)d_in[3];
    const float* bK  = (const float*)d_in[4];
    const float* WV  = (const float*)d_in[5];
    const float* bV  = (const float*)d_in[6];
    const int*   src = (const int*)d_in[7];
    const int*   dst = (const int*)d_in[8];
    float* out = (float*)d_out;
    float* ws  = (float*)d_ws;
    int*   wsi = (int*)d_ws;

    int*   cnt_out = wsi + O_CNTO;
    int*   cnt_in  = wsi + O_CNTI;
    int*   ovf_n   = wsi + O_OVFN;
    int2*  ovf     = (int2*)(wsi + O_OVF);
    int*   bin_cnt = wsi + O_BINC;
    int*   bucket  = wsi + O_BUCKET;
    int2*  pairs   = (int2*)(wsi + O_PAIRS);
    uint*  hb      = (uint*)(ws + O_HB);
    uint*  aggb    = (uint*)(ws + O_AGGB);
    uint*  wt      = (uint*)(ws + O_WT);
    uint*  qb      = (uint*)(ws + O_QB);
    uint*  kb      = (uint*)(ws + O_KB);
    uint*  vb      = (uint*)(ws + O_VB);

    // zero cnt_out, cnt_in, ovf_n, (ovf), bin_cnt in one shot
    hipMemsetAsync(wsi, 0, (O_BINC + NBINS) * sizeof(int), stream);

    k_wt<<<(3 * 8192 + 255) / 256, 256, 0, stream>>>(WQ, WK, WV, wt);

    k_part<<<(N_EDGES + EPB - 1) / EPB, 256, 0, stream>>>(src, dst, cnt_out,
                                                          bin_cnt, pairs);
    k_bins<<<NBINS, 256, 0, stream>>>(bin_cnt, pairs, cnt_in, bucket, ovf_n, ovf);

    k_hb<<<(N_NODES * 64 + 255) / 256, 256, 0, stream>>>(h, cnt_out, hb);

    k_agg<<<N_NODES / 4, 256, 0, stream>>>(cnt_in, bucket, ovf_n, ovf, hb, aggb);

    dim3 g_qkv((N_NODES + 127) / 128, 3);
    k_qkv<<<g_qkv, 256, 0, stream>>>(aggb, wt, bQ, bK, bV, qb, kb, vb);

    k_attn<<<N_NODES / 4, 256, 0, stream>>>(cnt_in, bucket, ovf_n, ovf,
                                            qb, kb, vb, out);
}

// Round 11
// 394.285 us; speedup vs baseline: 7.8401x; 1.0851x over previous
//
#include <hip/hip_runtime.h>

#define N_NODES 50000
#define N_EDGES 1600000
#define CAP 64            // bucket capacity per node; Poisson(32) tail @64 ~ 1e-7
#define OVF_CAP 8192

// Binned build parameters
#define BIN_SHIFT 7
#define BIN_NODES 128               // nodes per bin = 1<<BIN_SHIFT
#define NBINS 391                   // ceil(50000/128)
#define BIN_CAP 5120                // mean 4092, sigma ~64 -> 16 sigma headroom
#define EPB 4096                    // edges per k_part block
#define NPART_BLK 391               // ceil(N_EDGES/EPB)
#define NWT_BLK 96                  // ceil(3*8192/256)
#define NHB_BLK 12500               // ceil(N_NODES*64/256)

// Workspace element offsets (4-byte units). Peak ~77.4 MB.
#define O_CNTO   0         // int[50000]  out-degree
#define O_CNTI   50000     // int[50000]  in-degree (also bucket fill)
#define O_OVFN   100000    // int[1]      overflow count
#define O_OVF    100002    // int2[8192]  overflow (dst,src) pairs
#define O_BINC   116400    // int[391]    per-bin edge count (ends 116791 < 120000)
#define O_BUCKET 120000    // int[50000*64] src per slot
#define O_HB     3320000   // uint[3.2M]  bf16x2 h*norm_out
#define O_AGGB   6520000   // uint[3.2M]  bf16x2 agg rows (256 B/node)
#define O_WT     9720000   // uint[24576] bf16 W^T for Q,K,V: [3][128 n][64 k-pairs]
#define O_QB     9750000   // uint[3.2M]  bf16x2 Q rows (64 uints/node)
#define O_KV     12950000  // uint[6.4M]  interleaved bf16 K/V rows (512 B/node)
// pairs overlays qb/kv (NOT hb -- r10's fused launch B races bins-path pairs
// reads against hb-path writes if pairs sits at O_HB). Lifetime: written in
// launch A (disjoint from wt, which ends at 9744576), read in launch B's bins
// path (hb writes 3.32M..6.52M -- disjoint), dead before k_qkv writes qb/kv.
#define O_PAIRS  9750000   // int2[391*5120] = 16.0 MB, ends 13753840 < 19350000

typedef unsigned int uint;
typedef unsigned long long ulong64;
typedef __attribute__((ext_vector_type(8))) short short8;
typedef __attribute__((ext_vector_type(4))) float floatx4;

union U16 { uint4 u; short8 s; };

__device__ __forceinline__ uint f2bf2(float a, float b) {
    uint ua = __float_as_uint(a); ua = (ua + 0x7fffu + ((ua >> 16) & 1u)) >> 16;
    uint ub = __float_as_uint(b); ub = (ub + 0x7fffu + ((ub >> 16) & 1u)) >> 16;
    return ua | (ub << 16);
}
__device__ __forceinline__ float bflo(uint u) { return __uint_as_float(u << 16); }
__device__ __forceinline__ float bfhi(uint u) { return __uint_as_float(u & 0xffff0000u); }

// DPP cross-lane: VALU-only (no ds_bpermute, no lgkmcnt stalls).
// 0xB1 = quad_perm xor1; 0x4E = quad_perm xor2; 0x141 = row_half_mirror
// (mirror within 8 == xor7; after xor1+xor2 quads are uniform => full 8-sum).
template<int CTRL>
__device__ __forceinline__ float dpp_add8(float x) {
    int t = __builtin_amdgcn_update_dpp(0, __float_as_int(x), CTRL, 0xF, 0xF, true);
    return x + __int_as_float(t);
}
__device__ __forceinline__ float dpp_xor1(float x) {
    int t = __builtin_amdgcn_update_dpp(0, __float_as_int(x), 0xB1, 0xF, 0xF, true);
    return __int_as_float(t);
}

// Fused launch A: blocks [0,391) bin edges by dst>>7 (LDS histogram -> chunked
// reservation -> pair scatter; fire-and-forget cnt_out atomics); blocks
// [391,487) cast W^T to bf16. Disjoint outputs, both depend only on inputs.
__global__ __launch_bounds__(256) void k_part_wt(
    const int* __restrict__ src, const int* __restrict__ dst,
    int* cnt_out, int* bin_cnt, int2* __restrict__ pairs,
    const float* __restrict__ WQ, const float* __restrict__ WK,
    const float* __restrict__ WV, uint* __restrict__ wt)
{
    __shared__ int hist[NBINS];
    __shared__ int base[NBINS];
    const int t = threadIdx.x;

    if (blockIdx.x >= NPART_BLK) {            // ---- W^T cast path ----
        int idx = (blockIdx.x - NPART_BLK) * 256 + t;   // [0, 3*8192)
        if (idx < 3 * 8192) {
            int y = idx >> 13;
            int rem = idx & 8191;
            int k2 = rem >> 7;          // 0..63
            int n  = rem & 127;         // coalesced reads
            const float* W = (y == 0) ? WQ : (y == 1) ? WK : WV;
            float a = W[(2 * k2) * 128 + n];
            float b = W[(2 * k2 + 1) * 128 + n];
            wt[(y << 13) + (n << 6) + k2] = f2bf2(a, b);
        }
        return;
    }

    const int e0 = blockIdx.x * EPB;          // ---- edge-binning path ----

    for (int b = t; b < NBINS; b += 256) hist[b] = 0;
    __syncthreads();

    #pragma unroll
    for (int i = 0; i < EPB / 256; ++i) {
        int e = e0 + i * 256 + t;
        if (e < N_EDGES) {
            int d = dst[e];
            atomicAdd(&hist[d >> BIN_SHIFT], 1);
            atomicAdd(&cnt_out[src[e]], 1);
        }
    }
    __syncthreads();

    for (int b = t; b < NBINS; b += 256) {
        base[b] = atomicAdd(&bin_cnt[b], hist[b]);
        hist[b] = 0;                  // reuse as cursor
    }
    __syncthreads();

    #pragma unroll
    for (int i = 0; i < EPB / 256; ++i) {
        int e = e0 + i * 256 + t;
        if (e < N_EDGES) {
            int d = dst[e], s = src[e];   // L2-hot reload
            int bin = d >> BIN_SHIFT;
            int idx = base[bin] + atomicAdd(&hist[bin], 1);
            if (idx < BIN_CAP)            // statistically impossible to trip
                pairs[(size_t)bin * BIN_CAP + idx] = make_int2(d, s);
        }
    }
}

// Fused launch B: blocks [0,391) build buckets per bin (LDS-atomic position
// assignment, writes confined to 32 KB regions); blocks [391,12891) compute
// hb[n][j] = bf16(h[n][j]*rsqrt(max(deg_out,1))). cnt_out is final after A;
// pairs (at O_PAIRS) and hb are disjoint, so the two paths cannot race.
__global__ __launch_bounds__(256) void k_bins_hb(
    const int* __restrict__ bin_cnt, const int2* __restrict__ pairs,
    int* __restrict__ cnt_in, int* __restrict__ bucket,
    int* ovf_n, int2* __restrict__ ovf,
    const float* __restrict__ h, const int* __restrict__ cnt_out,
    uint* __restrict__ hb)
{
    __shared__ int lcnt[BIN_NODES];
    const int t = threadIdx.x;

    if (blockIdx.x >= NBINS) {                // ---- hb path ----
        int idx = (blockIdx.x - NBINS) * 256 + t;       // [0, N*64)
        if (idx < N_NODES * 64) {
            int n = idx >> 6;
            float no = rsqrtf(fmaxf((float)cnt_out[n], 1.0f));
            float2 hv = *(const float2*)(h + ((size_t)idx << 1));
            hb[idx] = f2bf2(hv.x * no, hv.y * no);
        }
        return;
    }

    const int b = blockIdx.x;                 // ---- bucket-build path ----
    for (int i = t; i < BIN_NODES; i += 256) lcnt[i] = 0;
    __syncthreads();

    const int nb = min(bin_cnt[b], BIN_CAP);
    const int2* pp = pairs + (size_t)b * BIN_CAP;
    for (int i = t; i < nb; i += 256) {
        int2 p = pp[i];                        // p.x = dst, p.y = src
        int pos = atomicAdd(&lcnt[p.x & (BIN_NODES - 1)], 1);
        if (pos < CAP) {
            bucket[((size_t)p.x << 6) + pos] = p.y;
        } else {                               // statistically never; safety net
            int o = atomicAdd(ovf_n, 1);
            if (o < OVF_CAP) ovf[o] = p;
        }
    }
    __syncthreads();

    const int node0 = b << BIN_SHIFT;
    for (int i = t; i < BIN_NODES; i += 256) {
        int n = node0 + i;
        if (n < N_NODES) cnt_in[n] = lcnt[i];  // total count incl. overflow
    }
}

// aggb[n] = bf16( rsqrt(max(deg_in,1)) * sum_{slots of n} hb[s] )
// Bucket row in-lane; readlane indices; 16-wide double-buffered row loads.
__global__ __launch_bounds__(256) void k_agg(
    const int* __restrict__ cnt_in, const int* __restrict__ bucket,
    const int* __restrict__ ovf_n, const int2* __restrict__ ovf,
    const uint* __restrict__ hb, uint* __restrict__ aggb)
{
    int n = blockIdx.x * 4 + (threadIdx.x >> 6);
    int lane = threadIdx.x & 63;
    int cnt = cnt_in[n];
    int m = min(cnt, CAP);
    const int* b = bucket + ((size_t)n << 6);
    int s_own = b[lane];                 // whole bucket row, one coalesced load
    float ax = 0.f, ay = 0.f;

    if (m > 0) {
        uint uA[16], uB[16];
        const int nb = (m + 15) >> 4;
        const int mm1 = m - 1;

#define AGLD(P, base) do { _Pragma("unroll")                                   \
        for (int j = 0; j < 16; ++j) {                                         \
            int sj = __builtin_amdgcn_readlane(s_own, min((base) + j, mm1));   \
            P[j] = hb[((uint)sj << 6) + (uint)lane];                           \
        } } while (0)
#define AGCMP(P, base) do { _Pragma("unroll")                                  \
        for (int j = 0; j < 16; ++j) {                                         \
            if ((base) + j < m) { ax += bflo(P[j]); ay += bfhi(P[j]); }        \
        } } while (0)

        AGLD(uA, 0);
        int t = 0;
        while (t + 1 < nb) {
            AGLD(uB, (t + 1) << 4);
            AGCMP(uA, t << 4);
            ++t;
            if (t + 1 < nb) {
                AGLD(uA, (t + 1) << 4);
                AGCMP(uB, t << 4);
                ++t;
            } else {
                AGCMP(uB, t << 4);
                ++t;
                break;
            }
        }
        if (t < nb) { AGCMP(uA, t << 4); }
#undef AGLD
#undef AGCMP
    }

    if (cnt > CAP) {                       // statistically never; correctness net
        int on = min(*ovf_n, OVF_CAP);
        for (int j = 0; j < on; ++j) {
            int2 p = ovf[j];
            if (p.x == n) {
                uint u = hb[((uint)p.y << 6) + (uint)lane];
                ax += bflo(u);
                ay += bfhi(u);
            }
        }
    }
    float ni = rsqrtf(fmaxf((float)cnt, 1.0f));
    aggb[((size_t)n << 6) + lane] = f2bf2(ax * ni, ay * ni);
}

// Fused QKV projection via bf16 MFMA. grid (391, 3): y=0 -> qb (bf16 rows),
// y=1 -> K half of interleaved kv, y=2 -> V half.
__global__ __launch_bounds__(256) void k_qkv(
    const uint* __restrict__ aggb, const uint* __restrict__ wt,
    const float* __restrict__ bQ, const float* __restrict__ bK,
    const float* __restrict__ bV,
    uint* __restrict__ qb, uint* __restrict__ kv)
{
    const int y = blockIdx.y;
    const int row0 = blockIdx.x * 128;
    const float* bias = (y == 0) ? bQ : (y == 1) ? bK : bV;

    __shared__ uint sA[128 * 68];   // A tile, row stride 68 uints

    const int t = threadIdx.x;
    for (int idx = t; idx < 128 * 16; idx += 256) {
        int r = idx >> 4, c4 = (idx & 15) << 2;
        int row = row0 + r;
        uint4 v = make_uint4(0u, 0u, 0u, 0u);
        if (row < N_NODES) v = *(const uint4*)(aggb + ((size_t)row << 6) + c4);
        *(uint4*)(&sA[r * 68 + c4]) = v;
    }
    __syncthreads();

    const int wave = t >> 6;
    const int lane = t & 63;
    const int mrow = lane & 15;     // m (A) / n (B) / col (C)
    const int kq   = lane >> 4;     // 0..3
    const int mbase = wave * 32;
    const uint* wty = wt + (y << 13);

    floatx4 acc[2][8];
    for (int a = 0; a < 2; ++a)
        for (int b = 0; b < 8; ++b)
            acc[a][b] = (floatx4){0.f, 0.f, 0.f, 0.f};

    for (int kc = 0; kc < 128; kc += 32) {
        int koff = (kc >> 1) + (kq << 2);    // uint offset within a row
        short8 afr[2], bfr[8];
        for (int mt = 0; mt < 2; ++mt) {
            U16 u; u.u = *(const uint4*)(&sA[(mbase + mt * 16 + mrow) * 68 + koff]);
            afr[mt] = u.s;
        }
        for (int nt = 0; nt < 8; ++nt) {
            U16 u; u.u = *(const uint4*)(wty + ((nt * 16 + mrow) << 6) + koff);
            bfr[nt] = u.s;
        }
        for (int mt = 0; mt < 2; ++mt)
            for (int nt = 0; nt < 8; ++nt)
                acc[mt][nt] = __builtin_amdgcn_mfma_f32_16x16x32_bf16(
                    afr[mt], bfr[nt], acc[mt][nt], 0, 0, 0);
    }

    // C/D: col = lane&15 (= mrow), row = kq*4 + reg. Pack pairs via DPP xor1.
    if (y == 0) {
        for (int mt = 0; mt < 2; ++mt) {
            int rbase = row0 + mbase + mt * 16 + kq * 4;
            for (int nt = 0; nt < 8; ++nt) {
                int c = nt * 16 + mrow;
                float bv = bias[c];
                for (int r = 0; r < 4; ++r) {
                    float v = fmaxf(acc[mt][nt][r] + bv, 0.f);
                    float pv = dpp_xor1(v);
                    int row = rbase + r;
                    if (((lane & 1) == 0) && row < N_NODES)
                        qb[((size_t)row << 6) + (c >> 1)] = f2bf2(v, pv);
                }
            }
        }
    } else {
        const int vo = (y == 2) ? 1 : 0;
        for (int mt = 0; mt < 2; ++mt) {
            int rbase = row0 + mbase + mt * 16 + kq * 4;
            for (int nt = 0; nt < 8; ++nt) {
                int c = nt * 16 + mrow;    // even for even lanes
                float bv = bias[c];
                for (int r = 0; r < 4; ++r) {
                    float v = fmaxf(acc[mt][nt][r] + bv, 0.f);
                    float pv = dpp_xor1(v);
                    int row = rbase + r;
                    if (((lane & 1) == 0) && row < N_NODES)
                        kv[((size_t)row << 7) + c + vo] = f2bf2(v, pv);
                }
            }
        }
    }
}

// score path: p-scale folded with log2(e); clamp at +/-10*log2(e); raw v_exp_f32.
#define SC_MUL 0.36067376022243085f   // 0.25 * log2(e)
#define SC_CLP 14.426950408889634f    // 10.0 * log2(e)

__device__ __forceinline__ void attn_step(uint2 kvp, float qx, float qy,
                                          float& ax, float& ay, float& zacc) {
    float p = bflo(kvp.x) * qx + bfhi(kvp.x) * qy;
    p = dpp_add8<0xB1>(p);    // + xor1
    p = dpp_add8<0x4E>(p);    // + xor2
    p = dpp_add8<0x141>(p);   // + xor7 (quad-uniform => == xor4)
    float tt = fminf(fmaxf(p * SC_MUL, -SC_CLP), SC_CLP);
    float sc;
    asm("v_exp_f32 %0, %1" : "=v"(sc) : "v"(tt));   // D = 2^S0
    ax += bflo(kvp.y) * sc;
    ay += bfhi(kvp.y) * sc;
    zacc += sc;
}

// Attention gather over interleaved KV. Bucket row in-lane + readlane indices;
// 8-wide double-buffered row loads (pA/pB, static indexing) -> the kv fetch of
// batch t+1 flies while batch t computes; no vmcnt(0) drain in the loop.
// At the measured random-gather fetch ceiling (~430 MB @ ~3.7 TB/s).
__global__ __launch_bounds__(256) void k_attn(
    const int* __restrict__ cnt_in, const int* __restrict__ bucket,
    const int* __restrict__ ovf_n, const int2* __restrict__ ovf,
    const uint* __restrict__ qb, const uint* __restrict__ kv,
    float* __restrict__ out)
{
    int n = blockIdx.x * 4 + (threadIdx.x >> 6);
    int lane = threadIdx.x & 63;
    int cnt = cnt_in[n];
    int m = min(cnt, CAP);
    const int* b = bucket + ((size_t)n << 6);
    int s_own = b[lane];                 // whole bucket row, one coalesced load

    uint qu = qb[((size_t)n << 6) + lane];
    float qx = bflo(qu), qy = bfhi(qu);
    float ax = 0.f, ay = 0.f, zacc = 0.f;
    const uint loff = (uint)(lane << 1);

    if (m > 0) {
        uint2 pA[8], pB[8];
        const int nb = (m + 7) >> 3;
        const int mm1 = m - 1;

#define KVLD(P, base) do { _Pragma("unroll")                                   \
        for (int j = 0; j < 8; ++j) {                                          \
            int sj = __builtin_amdgcn_readlane(s_own, min((base) + j, mm1));   \
            P[j] = *(const uint2*)(kv + (((uint)sj << 7) + loff));             \
        } } while (0)
#define KVCMP(P, base) do { _Pragma("unroll")                                  \
        for (int j = 0; j < 8; ++j) {                                          \
            if ((base) + j < m) attn_step(P[j], qx, qy, ax, ay, zacc);         \
        } } while (0)

        KVLD(pA, 0);
        int t = 0;
        while (t + 1 < nb) {
            KVLD(pB, (t + 1) << 3);
            KVCMP(pA, t << 3);
            ++t;
            if (t + 1 < nb) {
                KVLD(pA, (t + 1) << 3);
                KVCMP(pB, t << 3);
                ++t;
            } else {
                KVCMP(pB, t << 3);
                ++t;
                break;
            }
        }
        if (t < nb) { KVCMP(pA, t << 3); }
#undef KVLD
#undef KVCMP
    }

    if (cnt > CAP) {                       // statistically never; correctness net
        int on = min(*ovf_n, OVF_CAP);
        for (int j = 0; j < on; ++j) {
            int2 pr = ovf[j];
            if (pr.x == n) {
                uint2 p = *(const uint2*)(kv + (((uint)pr.y << 7) + loff));
                attn_step(p, qx, qy, ax, ay, zacc);
            }
        }
    }

    float inv = 1.0f / (zacc + 1e-6f);
    float2 o; o.x = ax * inv; o.y = ay * inv;
    *(float2*)(out + ((size_t)n << 7) + (lane << 1)) = o;
}

extern "C" void kernel_launch(void* const* d_in, const int* in_sizes, int n_in,
                              void* d_out, int out_size, void* d_ws, size_t ws_size,
                              hipStream_t stream) {
    const float* h   = (const float*)d_in[0];
    const float* WQ  = (const float*)d_in[1];
    const float* bQ  = (const float*)d_in[2];
    const float* WK  = (const float*)d_in[3];
    const float* bK  = (const float*)d_in[4];
    const float* WV  = (const float*)d_in[5];
    const float* bV  = (const float*)d_in[6];
    const int*   src = (const int*)d_in[7];
    const int*   dst = (const int*)d_in[8];
    float* out = (float*)d_out;
    float* ws  = (float*)d_ws;
    int*   wsi = (int*)d_ws;

    int*   cnt_out = wsi + O_CNTO;
    int*   cnt_in  = wsi + O_CNTI;
    int*   ovf_n   = wsi + O_OVFN;
    int2*  ovf     = (int2*)(wsi + O_OVF);
    int*   bin_cnt = wsi + O_BINC;
    int*   bucket  = wsi + O_BUCKET;
    int2*  pairs   = (int2*)(wsi + O_PAIRS);
    uint*  hb      = (uint*)(ws + O_HB);
    uint*  aggb    = (uint*)(ws + O_AGGB);
    uint*  wt      = (uint*)(ws + O_WT);
    uint*  qb      = (uint*)(ws + O_QB);
    uint*  kv      = (uint*)(ws + O_KV);

    // zero cnt_out, cnt_in, ovf_n, (ovf), bin_cnt in one shot
    hipMemsetAsync(wsi, 0, (O_BINC + NBINS) * sizeof(int), stream);

    k_part_wt<<<NPART_BLK + NWT_BLK, 256, 0, stream>>>(src, dst, cnt_out,
                                                       bin_cnt, pairs,
                                                       WQ, WK, WV, wt);

    k_bins_hb<<<NBINS + NHB_BLK, 256, 0, stream>>>(bin_cnt, pairs, cnt_in,
                                                   bucket, ovf_n, ovf,
                                                   h, cnt_out, hb);

    k_agg<<<N_NODES / 4, 256, 0, stream>>>(cnt_in, bucket, ovf_n, ovf, hb, aggb);

    dim3 g_qkv((N_NODES + 127) / 128, 3);
    k_qkv<<<g_qkv, 256, 0, stream>>>(aggb, wt, bQ, bK, bV, qb, kv);

    k_attn<<<N_NODES / 4, 256, 0, stream>>>(cnt_in, bucket, ovf_n, ovf,
                                            qb, kv, out);
}